// Round 3
// baseline (294.624 us; speedup 1.0000x reference)
//
#include <hip/hip_runtime.h>

#define D 64
#define NBMAX 256       // bucket count padded to 256 (real NB = ceil(N/512) = 196)
#define BCHUNK 4096     // edges per binpack block-iteration
#define CAP 8192        // LDS staging cap in bucket_csr (mean 6122, +26 sigma)
#define CAP_PACK 12288  // fixed per-bucket region in packed[] (self-allocating)

typedef unsigned short ushort_t;
typedef __attribute__((ext_vector_type(8))) short bf16x8;
typedef __attribute__((ext_vector_type(4))) float floatx4;

static __device__ __forceinline__ ushort_t f2bf(float x) {
  unsigned u = __float_as_uint(x);
  unsigned r = (u + 0x7FFF + ((u >> 16) & 1)) >> 16;  // RNE
  return (ushort_t)r;
}
static __device__ __forceinline__ float bf2f(ushort_t u) {
  return __uint_as_float(((unsigned)u) << 16);
}

// Accumulate one 16B (8 x bf16) row slice into 4 float2 accumulators.
static __device__ __forceinline__ void addrow(const uint4 v, float2& a0,
                                              float2& a1, float2& a2,
                                              float2& a3) {
  a0.x += __uint_as_float(v.x << 16);
  a0.y += __uint_as_float(v.x & 0xffff0000u);
  a1.x += __uint_as_float(v.y << 16);
  a1.y += __uint_as_float(v.y & 0xffff0000u);
  a2.x += __uint_as_float(v.z << 16);
  a2.y += __uint_as_float(v.z & 0xffff0000u);
  a3.x += __uint_as_float(v.w << 16);
  a3.y += __uint_as_float(v.w & 0xffff0000u);
}

// Load 4 row-slices (chunk CB..CB+3 of this group's edge list). Masked slots
// return zeros so accumulation is unconditional.
#define GLOAD4(T0, T1, T2, T3, IR, OFF, CB)                                    \
  do {                                                                         \
    const int s0_ = __shfl((IR), gbase + (OFF) + 0, 64);                       \
    const int s1_ = __shfl((IR), gbase + (OFF) + 1, 64);                       \
    const int s2_ = __shfl((IR), gbase + (OFF) + 2, 64);                       \
    const int s3_ = __shfl((IR), gbase + (OFF) + 3, 64);                       \
    T0 = ((CB) + 0 < m) ? *(const uint4*)(tab + ((size_t)s0_ << 6) + off16)    \
                        : z4;                                                  \
    T1 = ((CB) + 1 < m) ? *(const uint4*)(tab + ((size_t)s1_ << 6) + off16)    \
                        : z4;                                                  \
    T2 = ((CB) + 2 < m) ? *(const uint4*)(tab + ((size_t)s2_ << 6) + off16)    \
                        : z4;                                                  \
    T3 = ((CB) + 3 < m) ? *(const uint4*)(tab + ((size_t)s3_ << 6) + off16)    \
                        : z4;                                                  \
  } while (0)

#define ACC4(T0, T1, T2, T3)    \
  do {                          \
    addrow(T0, c0, c1, c2, c3); \
    addrow(T1, c0, c1, c2, c3); \
    addrow(T2, c0, c1, c2, c3); \
    addrow(T3, c0, c1, c2, c3); \
  } while (0)

// Group-per-node gather: 8-lane group owns node (e0..e1), each lane owns a
// fixed 16B column slice. Up to 32 edges via prefetched indices + 2-deep
// pipelined chunks of 4 row loads; deg>32 tail is a rare serial loop.
// Must be called by all 64 lanes of the wave (shfl participation).
static __device__ __forceinline__ void gather_node8(
    const ushort_t* __restrict__ tab, const int* __restrict__ csr_src, int e0,
    int e1, int sub8, int gbase, float2& c0, float2& c1, float2& c2,
    float2& c3) {
  const int off16 = sub8 << 3;  // ushort units: 16B per lane
  const int m = e1 - e0;
  // prefetch up to 32 indices (4 independent loads per lane)
  const int ir0 = (e0 + 0 + sub8 < e1) ? csr_src[e0 + 0 + sub8] : 0;
  const int ir1 = (e0 + 8 + sub8 < e1) ? csr_src[e0 + 8 + sub8] : 0;
  const int ir2 = (e0 + 16 + sub8 < e1) ? csr_src[e0 + 16 + sub8] : 0;
  const int ir3 = (e0 + 24 + sub8 < e1) ? csr_src[e0 + 24 + sub8] : 0;
  // wave-uniform chunk count from max degree (m uniform within group)
  int mm = m;
  mm = max(mm, __shfl_xor(mm, 8, 64));
  mm = max(mm, __shfl_xor(mm, 16, 64));
  mm = max(mm, __shfl_xor(mm, 32, 64));
  const int nch = __builtin_amdgcn_readfirstlane(min((mm + 3) >> 2, 8));
  const uint4 z4 = make_uint4(0, 0, 0, 0);
  uint4 A0, A1, A2, A3, B0, B1, B2, B3;
  if (nch > 0) {
    GLOAD4(A0, A1, A2, A3, ir0, 0, 0);
    if (nch > 1) GLOAD4(B0, B1, B2, B3, ir0, 4, 4);
    ACC4(A0, A1, A2, A3);
    if (nch > 1) {
      if (nch > 2) GLOAD4(A0, A1, A2, A3, ir1, 0, 8);
      ACC4(B0, B1, B2, B3);
      if (nch > 2) {
        if (nch > 3) GLOAD4(B0, B1, B2, B3, ir1, 4, 12);
        ACC4(A0, A1, A2, A3);
        if (nch > 3) {
          if (nch > 4) GLOAD4(A0, A1, A2, A3, ir2, 0, 16);
          ACC4(B0, B1, B2, B3);
          if (nch > 4) {
            if (nch > 5) GLOAD4(B0, B1, B2, B3, ir2, 4, 20);
            ACC4(A0, A1, A2, A3);
            if (nch > 5) {
              if (nch > 6) GLOAD4(A0, A1, A2, A3, ir3, 0, 24);
              ACC4(B0, B1, B2, B3);
              if (nch > 6) {
                if (nch > 7) GLOAD4(B0, B1, B2, B3, ir3, 4, 28);
                ACC4(A0, A1, A2, A3);
                if (nch > 7) ACC4(B0, B1, B2, B3);
              }
            }
          }
        }
      }
    }
  }
  // rare deg>32 tail (group-uniform loop, exec-masked per group)
  for (int eb = e0 + 32; eb < e1; ++eb) {
    const int ii = csr_src[eb];
    const uint4 tv = *(const uint4*)(tab + ((size_t)ii << 6) + off16);
    addrow(tv, c0, c1, c2, c3);
  }
}

// ---- K1: MFMA GEMM + residual for layer 1, plus gtail/off-tail init ----
__global__ __launch_bounds__(256) void gemm_res_mfma_kernel(
    const float* __restrict__ x, const float* __restrict__ W,
    const float* __restrict__ Wr, const float* __restrict__ br,
    ushort_t* __restrict__ xw, ushort_t* __restrict__ res, int n_nodes,
    int* __restrict__ gtail, int* __restrict__ off_tail, int n_edges) {
  if (blockIdx.x == 0) {
    if (threadIdx.x < NBMAX) gtail[threadIdx.x] = (int)threadIdx.x * CAP_PACK;
    if (threadIdx.x == 0) *off_tail = n_edges;  // csr_off[n_nodes]
  }
  const int lane = threadIdx.x & 63;
  const int wid = threadIdx.x >> 6;
  const int sub = lane & 15;
  const int q = lane >> 4;

  bf16x8 bW[4][2], bR[4][2];
#pragma unroll
  for (int t = 0; t < 4; ++t) {
#pragma unroll
    for (int s = 0; s < 2; ++s) {
      bf16x8 fw, fr;
#pragma unroll
      for (int j = 0; j < 8; ++j) {
        const int k = s * 32 + q * 8 + j;
        const int c = t * 16 + sub;
        fw[j] = (short)f2bf(W[k * D + c]);
        fr[j] = (short)f2bf(Wr[k * D + c]);
      }
      bW[t][s] = fw;
      bR[t][s] = fr;
    }
  }
  float brv[4];
#pragma unroll
  for (int t = 0; t < 4; ++t) brv[t] = br[t * 16 + sub];

  const int n_tiles = (n_nodes + 15) >> 4;
  const int wave_id = blockIdx.x * 4 + wid;
  const int n_waves = gridDim.x * 4;
  for (int tile = wave_id; tile < n_tiles; tile += n_waves) {
    const int n0 = tile << 4;
    const bool full = (n0 + 16 <= n_nodes);
    bf16x8 a0h, a0l, a1h, a1l;
    float v[16];
    if (full) {
      const float* xp = x + (size_t)(n0 + sub) * D + q * 8;
      *(float4*)(v + 0)  = *(const float4*)(xp);
      *(float4*)(v + 4)  = *(const float4*)(xp + 4);
      *(float4*)(v + 8)  = *(const float4*)(xp + 32);
      *(float4*)(v + 12) = *(const float4*)(xp + 36);
    } else {
      const bool ok = (n0 + sub) < n_nodes;
      const float* xp = x + (size_t)(n0 + sub) * D + q * 8;
#pragma unroll
      for (int j = 0; j < 8; ++j) {
        v[j] = ok ? xp[j] : 0.f;
        v[8 + j] = ok ? xp[32 + j] : 0.f;
      }
    }
#pragma unroll
    for (int j = 0; j < 8; ++j) {
      const ushort_t h0 = f2bf(v[j]);
      a0h[j] = (short)h0;
      a0l[j] = (short)f2bf(v[j] - bf2f(h0));
      const ushort_t h1 = f2bf(v[8 + j]);
      a1h[j] = (short)h1;
      a1l[j] = (short)f2bf(v[8 + j] - bf2f(h1));
    }
    floatx4 accW[4], accR[4];
#pragma unroll
    for (int t = 0; t < 4; ++t) {
      accW[t] = (floatx4){0.f, 0.f, 0.f, 0.f};
      accR[t] = (floatx4){0.f, 0.f, 0.f, 0.f};
    }
#pragma unroll
    for (int t = 0; t < 4; ++t) {
      accW[t] = __builtin_amdgcn_mfma_f32_16x16x32_bf16(a0h, bW[t][0], accW[t], 0, 0, 0);
      accW[t] = __builtin_amdgcn_mfma_f32_16x16x32_bf16(a0l, bW[t][0], accW[t], 0, 0, 0);
      accW[t] = __builtin_amdgcn_mfma_f32_16x16x32_bf16(a1h, bW[t][1], accW[t], 0, 0, 0);
      accW[t] = __builtin_amdgcn_mfma_f32_16x16x32_bf16(a1l, bW[t][1], accW[t], 0, 0, 0);
      accR[t] = __builtin_amdgcn_mfma_f32_16x16x32_bf16(a0h, bR[t][0], accR[t], 0, 0, 0);
      accR[t] = __builtin_amdgcn_mfma_f32_16x16x32_bf16(a0l, bR[t][0], accR[t], 0, 0, 0);
      accR[t] = __builtin_amdgcn_mfma_f32_16x16x32_bf16(a1h, bR[t][1], accR[t], 0, 0, 0);
      accR[t] = __builtin_amdgcn_mfma_f32_16x16x32_bf16(a1l, bR[t][1], accR[t], 0, 0, 0);
    }
    if (full) {
#pragma unroll
      for (int t = 0; t < 4; ++t) {
#pragma unroll
        for (int i = 0; i < 4; ++i) {
          const size_t r = (size_t)(n0 + q * 4 + i) * D + t * 16 + sub;
          xw[r] = f2bf(accW[t][i]);
          res[r] = f2bf(fmaxf(accR[t][i] + brv[t], 0.f));
        }
      }
    } else {
#pragma unroll
      for (int t = 0; t < 4; ++t) {
#pragma unroll
        for (int i = 0; i < 4; ++i) {
          const int rr = n0 + q * 4 + i;
          if (rr < n_nodes) {
            const size_t r = (size_t)rr * D + t * 16 + sub;
            xw[r] = f2bf(accW[t][i]);
            res[r] = f2bf(fmaxf(accR[t][i] + brv[t], 0.f));
          }
        }
      }
    }
  }
}

// ---- K2: chunk-local LDS sort by bucket, coalesced segment writes into
// per-bucket FIXED regions (b*CAP_PACK). Self-allocating via gtail atomics.
__global__ __launch_bounds__(256) void binpack_kernel(
    const int* __restrict__ src, const int* __restrict__ dst,
    int* __restrict__ gtail, unsigned* __restrict__ packed, int n_edges) {
  __shared__ int start[NBMAX], cur[NBMAX], gpos[NBMAX];
  __shared__ unsigned sorted[BCHUNK];
  __shared__ unsigned char bktid[BCHUNK];
  const int t = threadIdx.x;
  const int nchunk = (n_edges + BCHUNK - 1) / BCHUNK;
  for (int c = blockIdx.x; c < nchunk; c += gridDim.x) {
    cur[t] = 0;
    __syncthreads();
    const int e0 = c * BCHUNK;
    const int m = min(BCHUNK, n_edges - e0);
    int bk[16];
    unsigned pk[16];
#pragma unroll
    for (int k = 0; k < 16; ++k) {
      const int e = e0 + k * 256 + t;
      if (e < n_edges) {
        const int d = dst[e];
        const int s = src[e];
        bk[k] = d >> 9;
        pk[k] = ((unsigned)(d & 511) << 23) | (unsigned)s;
        atomicAdd(&cur[bk[k]], 1);
      } else {
        bk[k] = -1;
      }
    }
    __syncthreads();
    const int h = cur[t];
    start[t] = h;
    __syncthreads();
    for (int off = 1; off < NBMAX; off <<= 1) {
      const int v = (t >= off) ? start[t - off] : 0;
      __syncthreads();
      start[t] += v;
      __syncthreads();
    }
    const int excl = start[t] - h;
    __syncthreads();
    start[t] = excl;
    cur[t] = excl;
    __syncthreads();
#pragma unroll
    for (int k = 0; k < 16; ++k) {
      if (bk[k] >= 0) {
        const int pos = atomicAdd(&cur[bk[k]], 1);
        sorted[pos] = pk[k];
        bktid[pos] = (unsigned char)bk[k];
      }
    }
    __syncthreads();
    if (h > 0) gpos[t] = atomicAdd(&gtail[t], h);
    __syncthreads();
    for (int j = t; j < m; j += 256) {
      const int b = bktid[j];
      packed[gpos[b] + j - start[b]] = sorted[j];
    }
    __syncthreads();
  }
}

// ---- K3: one block per bucket. Redundant 196-entry LDS scan of gtail-derived
// counts -> exact bases; then LDS counting sort; coalesced csr_off/csr_src out.
__global__ __launch_bounds__(256) void bucket_csr_kernel(
    const unsigned* __restrict__ packed, const int* __restrict__ gtail,
    int* __restrict__ csr_off, int* __restrict__ csr_src, int n_nodes,
    int nbuckets) {
  __shared__ int scnt[NBMAX], sexc[NBMAX];
  __shared__ int sc[2][512];
  __shared__ int cur[512];
  __shared__ unsigned outbuf[CAP];
  const int b = blockIdx.x;
  const int t = threadIdx.x;
  // exact bucket bases from final gtails (count = gtail[b] - b*CAP_PACK)
  const int cb = (t < nbuckets) ? (gtail[t] - t * CAP_PACK) : 0;
  scnt[t] = cb;
  sexc[t] = cb;
  __syncthreads();
  for (int off = 1; off < NBMAX; off <<= 1) {
    const int v = (t >= off) ? sexc[t - off] : 0;
    __syncthreads();
    sexc[t] += v;
    __syncthreads();
  }
  sexc[t] -= scnt[t];  // exclusive
  __syncthreads();
  const int base = sexc[b];
  const int cntE = scnt[b];
  const unsigned* pk = packed + (size_t)b * CAP_PACK;

  const int n0 = b << 9;
  const int nn = min(512, n_nodes - n0);
  cur[t] = 0;
  cur[t + 256] = 0;
  __syncthreads();
  for (int i = t; i < cntE; i += 256) atomicAdd(&cur[pk[i] >> 23], 1);
  __syncthreads();
  const int h0 = cur[t];
  const int h1 = cur[t + 256];
  sc[0][t] = h0;
  sc[0][t + 256] = h1;
  __syncthreads();
  int pin = 0;
  for (int off = 1; off < 512; off <<= 1) {
    sc[1 - pin][t] = sc[pin][t] + ((t >= off) ? sc[pin][t - off] : 0);
    sc[1 - pin][t + 256] =
        sc[pin][t + 256] + ((t + 256 >= off) ? sc[pin][t + 256 - off] : 0);
    __syncthreads();
    pin ^= 1;
  }
  const int excl0 = sc[pin][t] - h0;
  const int excl1 = sc[pin][t + 256] - h1;
  if (t < nn) csr_off[n0 + t] = base + excl0;
  if (t + 256 < nn) csr_off[n0 + t + 256] = base + excl1;
  cur[t] = excl0;
  cur[t + 256] = excl1;
  __syncthreads();
  if (cntE <= CAP) {
    for (int i = t; i < cntE; i += 256) {
      const unsigned u = pk[i];
      const int pos = atomicAdd(&cur[u >> 23], 1);
      outbuf[pos] = u & 0x7FFFFFu;
    }
    __syncthreads();
    for (int j = t; j < cntE; j += 256) csr_src[base + j] = (int)outbuf[j];
  } else {  // overflow fallback
    for (int i = t; i < cntE; i += 256) {
      const unsigned u = pk[i];
      const int pos = atomicAdd(&cur[u >> 23], 1);
      csr_src[base + pos] = (int)(u & 0x7FFFFFu);
    }
  }
}

// ---- K4: fused gather1 + combine + gemm2, 32-row tiles ----
// Weights (W2,Wr2 fragments) and b1 live in LDS so the gather phase carries
// no persistent weight VGPRs (target <=64 VGPR -> 6+ blocks/CU).
__global__ __launch_bounds__(256, 6) void gather_gemm_kernel(
    const ushort_t* __restrict__ xw1, const ushort_t* __restrict__ res1,
    const float* __restrict__ b1v, const int* __restrict__ csr_off,
    const int* __restrict__ csr_src, const float* __restrict__ W2,
    const float* __restrict__ Wr2, const float* __restrict__ br2,
    ushort_t* __restrict__ xw2, ushort_t* __restrict__ res2, int n_nodes) {
  const int lane = threadIdx.x & 63;
  const int w = threadIdx.x >> 6;
  const int sub = lane & 15;  // gemm phase
  const int q = lane >> 4;    // gemm phase
  const int sub8 = lane & 7;  // gather phase
  const int g = lane >> 3;
  const int gbase = lane & 56;
  __shared__ float h_tile[32][68];
  __shared__ bf16x8 wfrag[2][8][64];  // [mat][(w*2+s)][lane], 16 KB
  __shared__ float b1s[64];

  // one-time loader: per-wave weight fragments -> LDS
#pragma unroll
  for (int s = 0; s < 2; ++s) {
    bf16x8 fw, fr;
#pragma unroll
    for (int j = 0; j < 8; ++j) {
      const int k = s * 32 + q * 8 + j;
      const int c = w * 16 + sub;
      fw[j] = (short)f2bf(W2[k * D + c]);
      fr[j] = (short)f2bf(Wr2[k * D + c]);
    }
    wfrag[0][w * 2 + s][lane] = fw;
    wfrag[1][w * 2 + s][lane] = fr;
  }
  if (threadIdx.x < 64) b1s[threadIdx.x] = b1v[threadIdx.x];
  const float brl2 = br2[w * 16 + sub];
  __syncthreads();

  const int n_tiles = (n_nodes + 31) >> 5;
  for (int tile = blockIdx.x; tile < n_tiles; tile += gridDim.x) {
    const int n0 = tile << 5;
    const int nb = n0 + w * 8;
    // 9 consecutive csr_off entries via lanes 0..8 (clamped; csr_off[n_nodes]
    // valid == n_edges, set by K1). Clamped nodes get m=0.
    const int offv = csr_off[min(nb + (lane < 9 ? lane : 8), n_nodes)];
    const int e0 = __shfl(offv, g, 64);
    const int e1 = __shfl(offv, g + 1, 64);
    float2 c0 = {0.f, 0.f}, c1 = {0.f, 0.f}, c2 = {0.f, 0.f}, c3 = {0.f, 0.f};
    gather_node8(xw1, csr_src, e0, e1, sub8, gbase, c0, c1, c2, c3);
    const int n = nb + g;
    const int row = (w << 3) + g;
    if (n < n_nodes) {
      const uint4 rv = *(const uint4*)(res1 + ((size_t)n << 6) + (sub8 << 3));
      const float2 bz0 = *(const float2*)(&b1s[sub8 * 8 + 0]);
      const float2 bz1 = *(const float2*)(&b1s[sub8 * 8 + 2]);
      const float2 bz2 = *(const float2*)(&b1s[sub8 * 8 + 4]);
      const float2 bz3 = *(const float2*)(&b1s[sub8 * 8 + 6]);
      float4 lo, hi;
      lo.x = fmaxf(c0.x + bz0.x, 0.f) + __uint_as_float(rv.x << 16);
      lo.y = fmaxf(c0.y + bz0.y, 0.f) + __uint_as_float(rv.x & 0xffff0000u);
      lo.z = fmaxf(c1.x + bz1.x, 0.f) + __uint_as_float(rv.y << 16);
      lo.w = fmaxf(c1.y + bz1.y, 0.f) + __uint_as_float(rv.y & 0xffff0000u);
      hi.x = fmaxf(c2.x + bz2.x, 0.f) + __uint_as_float(rv.z << 16);
      hi.y = fmaxf(c2.y + bz2.y, 0.f) + __uint_as_float(rv.z & 0xffff0000u);
      hi.z = fmaxf(c3.x + bz3.x, 0.f) + __uint_as_float(rv.w << 16);
      hi.w = fmaxf(c3.y + bz3.y, 0.f) + __uint_as_float(rv.w & 0xffff0000u);
      *(float4*)(&h_tile[row][sub8 * 8]) = lo;
      *(float4*)(&h_tile[row][sub8 * 8 + 4]) = hi;
    } else {
      *(float4*)(&h_tile[row][sub8 * 8]) = make_float4(0.f, 0.f, 0.f, 0.f);
      *(float4*)(&h_tile[row][sub8 * 8 + 4]) = make_float4(0.f, 0.f, 0.f, 0.f);
    }
    __syncthreads();
    // ---- gemm2: wave w computes cols w*16..+15 for both 16-row sub-tiles ----
#pragma unroll
    for (int st = 0; st < 2; ++st) {
      const float* hrow = &h_tile[st * 16 + sub][0];
      bf16x8 a0h, a0l, a1h, a1l;
      {
        const float4 p0 = *(const float4*)(hrow + q * 8);
        const float4 p1 = *(const float4*)(hrow + q * 8 + 4);
        const float vv[8] = {p0.x, p0.y, p0.z, p0.w, p1.x, p1.y, p1.z, p1.w};
#pragma unroll
        for (int j = 0; j < 8; ++j) {
          const ushort_t h0 = f2bf(vv[j]);
          a0h[j] = (short)h0;
          a0l[j] = (short)f2bf(vv[j] - bf2f(h0));
        }
      }
      {
        const float4 p2 = *(const float4*)(hrow + 32 + q * 8);
        const float4 p3 = *(const float4*)(hrow + 32 + q * 8 + 4);
        const float vv[8] = {p2.x, p2.y, p2.z, p2.w, p3.x, p3.y, p3.z, p3.w};
#pragma unroll
        for (int j = 0; j < 8; ++j) {
          const ushort_t h1 = f2bf(vv[j]);
          a1h[j] = (short)h1;
          a1l[j] = (short)f2bf(vv[j] - bf2f(h1));
        }
      }
      const bf16x8 w0 = wfrag[0][w * 2 + 0][lane];
      const bf16x8 w1 = wfrag[0][w * 2 + 1][lane];
      const bf16x8 r0 = wfrag[1][w * 2 + 0][lane];
      const bf16x8 r1 = wfrag[1][w * 2 + 1][lane];
      floatx4 accW = (floatx4){0.f, 0.f, 0.f, 0.f};
      floatx4 accR = (floatx4){0.f, 0.f, 0.f, 0.f};
      accW = __builtin_amdgcn_mfma_f32_16x16x32_bf16(a0h, w0, accW, 0, 0, 0);
      accW = __builtin_amdgcn_mfma_f32_16x16x32_bf16(a0l, w0, accW, 0, 0, 0);
      accW = __builtin_amdgcn_mfma_f32_16x16x32_bf16(a1h, w1, accW, 0, 0, 0);
      accW = __builtin_amdgcn_mfma_f32_16x16x32_bf16(a1l, w1, accW, 0, 0, 0);
      accR = __builtin_amdgcn_mfma_f32_16x16x32_bf16(a0h, r0, accR, 0, 0, 0);
      accR = __builtin_amdgcn_mfma_f32_16x16x32_bf16(a0l, r0, accR, 0, 0, 0);
      accR = __builtin_amdgcn_mfma_f32_16x16x32_bf16(a1h, r1, accR, 0, 0, 0);
      accR = __builtin_amdgcn_mfma_f32_16x16x32_bf16(a1l, r1, accR, 0, 0, 0);
#pragma unroll
      for (int i = 0; i < 4; ++i) {
        const int rr = n0 + st * 16 + q * 4 + i;
        if (rr < n_nodes) {
          const size_t r = (size_t)rr * D + w * 16 + sub;
          xw2[r] = f2bf(accW[i]);
          res2[r] = f2bf(fmaxf(accR[i] + brl2, 0.f));
        }
      }
    }
    __syncthreads();  // h_tile reused next tile
  }
}

// ---- K5: final gather + combine -> out (group-per-node gather) ----
// Bias re-loaded from global at combine (L1-resident) -> no persistent bias
// VGPRs; launch_bounds forces <=64 VGPR for 8 waves/SIMD.
__global__ __launch_bounds__(256, 8) void gather_combine_kernel(
    const ushort_t* __restrict__ xw, const ushort_t* __restrict__ res,
    const float* __restrict__ b, const int* __restrict__ csr_off,
    const int* __restrict__ csr_src, float* __restrict__ out, int n_nodes) {
  const int lane = threadIdx.x & 63;
  const int w = threadIdx.x >> 6;
  const int sub8 = lane & 7;
  const int g = lane >> 3;
  const int gbase = lane & 56;
  const int n_tiles = (n_nodes + 31) >> 5;
  for (int tile = blockIdx.x; tile < n_tiles; tile += gridDim.x) {
    const int nb = (tile << 5) + w * 8;
    const int offv = csr_off[min(nb + (lane < 9 ? lane : 8), n_nodes)];
    const int e0 = __shfl(offv, g, 64);
    const int e1 = __shfl(offv, g + 1, 64);
    float2 c0 = {0.f, 0.f}, c1 = {0.f, 0.f}, c2 = {0.f, 0.f}, c3 = {0.f, 0.f};
    gather_node8(xw, csr_src, e0, e1, sub8, gbase, c0, c1, c2, c3);
    const int n = nb + g;
    if (n < n_nodes) {
      const uint4 rv = *(const uint4*)(res + ((size_t)n << 6) + (sub8 << 3));
      const float4 blo = *(const float4*)(b + sub8 * 8);
      const float4 bhi = *(const float4*)(b + sub8 * 8 + 4);
      float4 lo, hi;
      lo.x = fmaxf(c0.x + blo.x, 0.f) + __uint_as_float(rv.x << 16);
      lo.y = fmaxf(c0.y + blo.y, 0.f) + __uint_as_float(rv.x & 0xffff0000u);
      lo.z = fmaxf(c1.x + blo.z, 0.f) + __uint_as_float(rv.y << 16);
      lo.w = fmaxf(c1.y + blo.w, 0.f) + __uint_as_float(rv.y & 0xffff0000u);
      hi.x = fmaxf(c2.x + bhi.x, 0.f) + __uint_as_float(rv.z << 16);
      hi.y = fmaxf(c2.y + bhi.y, 0.f) + __uint_as_float(rv.z & 0xffff0000u);
      hi.z = fmaxf(c3.x + bhi.z, 0.f) + __uint_as_float(rv.w << 16);
      hi.w = fmaxf(c3.y + bhi.w, 0.f) + __uint_as_float(rv.w & 0xffff0000u);
      *(float4*)(out + ((size_t)n << 6) + sub8 * 8) = lo;
      *(float4*)(out + ((size_t)n << 6) + sub8 * 8 + 4) = hi;
    }
  }
}

extern "C" void kernel_launch(void* const* d_in, const int* in_sizes, int n_in,
                              void* d_out, int out_size, void* d_ws, size_t ws_size,
                              hipStream_t stream) {
  const float* feats = (const float*)d_in[0];
  const float* W1  = (const float*)d_in[1];
  const float* b1  = (const float*)d_in[2];
  const float* Wr1 = (const float*)d_in[3];
  const float* br1 = (const float*)d_in[4];
  const float* W2  = (const float*)d_in[5];
  const float* b2  = (const float*)d_in[6];
  const float* Wr2 = (const float*)d_in[7];
  const float* br2 = (const float*)d_in[8];
  const int* src = (const int*)d_in[9];
  const int* dst = (const int*)d_in[10];
  const int n_nodes = in_sizes[0] / D;
  const int n_edges = in_sizes[9];
  float* out = (float*)d_out;

  const int nbuckets = (n_nodes + 511) >> 9;  // 196 for N=100k

  // workspace layout (~70 MB)
  ushort_t* xw1 = (ushort_t*)d_ws;                     // n_nodes*D bf16
  ushort_t* res1 = xw1 + (size_t)n_nodes * D;
  ushort_t* xw2 = res1 + (size_t)n_nodes * D;
  ushort_t* res2 = xw2 + (size_t)n_nodes * D;
  int* csr_off = (int*)(res2 + (size_t)n_nodes * D);   // n_nodes+1
  int* csr_src = csr_off + (n_nodes + 1);              // n_edges
  int* gtail = csr_src + n_edges;                      // NBMAX
  unsigned* packed = (unsigned*)(gtail + NBMAX);       // NBMAX*CAP_PACK

  const int tiles32 = (n_nodes + 31) / 32;             // 3125 for N=100k
  const int gblocks = tiles32 < 16384 ? tiles32 : 16384;
  const int nchunk = (n_edges + BCHUNK - 1) / BCHUNK;
  const int pblocks = nchunk < 1024 ? nchunk : 1024;
  dim3 blk(256);

  // K1: layer-1 dual GEMM (also inits gtail + csr_off tail for the CSR build)
  gemm_res_mfma_kernel<<<1024, blk, 0, stream>>>(
      feats, W1, Wr1, br1, xw1, res1, n_nodes, gtail, csr_off + n_nodes, n_edges);
  // K2: bucket the edge list (self-allocating fixed regions)
  binpack_kernel<<<pblocks, blk, 0, stream>>>(src, dst, gtail, packed, n_edges);
  // K3: per-bucket counting sort -> csr_off, csr_src
  bucket_csr_kernel<<<nbuckets, blk, 0, stream>>>(packed, gtail, csr_off,
                                                  csr_src, n_nodes, nbuckets);
  // K4: gather1 + combine + layer-2 dual GEMM (h1 stays in LDS)
  gather_gemm_kernel<<<gblocks, blk, 0, stream>>>(
      xw1, res1, b1, csr_off, csr_src, W2, Wr2, br2, xw2, res2, n_nodes);
  // K5: final gather + combine -> out
  gather_combine_kernel<<<gblocks, blk, 0, stream>>>(
      xw2, res2, b2, csr_off, csr_src, out, n_nodes);
}

// Round 4
// 254.534 us; speedup vs baseline: 1.1575x; 1.1575x over previous
//
#include <hip/hip_runtime.h>

#define D 64
#define NBMAX 256       // bucket count padded to 256 (real NB = ceil(N/512) = 196)
#define BCHUNK 4096     // edges per binpack block-iteration
#define CAP 8192        // LDS staging cap in bucket_csr (mean 6122, +26 sigma)
#define CAP_PACK 12288  // fixed per-bucket region in packed[] (self-allocating)

typedef unsigned short ushort_t;
typedef __attribute__((ext_vector_type(8))) short bf16x8;
typedef __attribute__((ext_vector_type(4))) float floatx4;

static __device__ __forceinline__ ushort_t f2bf(float x) {
  unsigned u = __float_as_uint(x);
  unsigned r = (u + 0x7FFF + ((u >> 16) & 1)) >> 16;  // RNE
  return (ushort_t)r;
}
static __device__ __forceinline__ float bf2f(ushort_t u) {
  return __uint_as_float(((unsigned)u) << 16);
}

// Accumulate one 16B (8 x bf16) row slice into 4 float2 accumulators.
static __device__ __forceinline__ void addrow(const uint4 v, float2& a0,
                                              float2& a1, float2& a2,
                                              float2& a3) {
  a0.x += __uint_as_float(v.x << 16);
  a0.y += __uint_as_float(v.x & 0xffff0000u);
  a1.x += __uint_as_float(v.y << 16);
  a1.y += __uint_as_float(v.y & 0xffff0000u);
  a2.x += __uint_as_float(v.z << 16);
  a2.y += __uint_as_float(v.z & 0xffff0000u);
  a3.x += __uint_as_float(v.w << 16);
  a3.y += __uint_as_float(v.w & 0xffff0000u);
}

// Load 4 row-slices (chunk CB..CB+3 of this group's edge list). Masked slots
// return zeros so accumulation is unconditional.
#define GLOAD4(T0, T1, T2, T3, IR, OFF, CB)                                    \
  do {                                                                         \
    const int s0_ = __shfl((IR), gbase + (OFF) + 0, 64);                       \
    const int s1_ = __shfl((IR), gbase + (OFF) + 1, 64);                       \
    const int s2_ = __shfl((IR), gbase + (OFF) + 2, 64);                       \
    const int s3_ = __shfl((IR), gbase + (OFF) + 3, 64);                       \
    T0 = ((CB) + 0 < m) ? *(const uint4*)(tab + ((size_t)s0_ << 6) + off16)    \
                        : z4;                                                  \
    T1 = ((CB) + 1 < m) ? *(const uint4*)(tab + ((size_t)s1_ << 6) + off16)    \
                        : z4;                                                  \
    T2 = ((CB) + 2 < m) ? *(const uint4*)(tab + ((size_t)s2_ << 6) + off16)    \
                        : z4;                                                  \
    T3 = ((CB) + 3 < m) ? *(const uint4*)(tab + ((size_t)s3_ << 6) + off16)    \
                        : z4;                                                  \
  } while (0)

#define ACC4(T0, T1, T2, T3)    \
  do {                          \
    addrow(T0, c0, c1, c2, c3); \
    addrow(T1, c0, c1, c2, c3); \
    addrow(T2, c0, c1, c2, c3); \
    addrow(T3, c0, c1, c2, c3); \
  } while (0)

// Group-per-node gather: 8-lane group owns node (e0..e1), each lane owns a
// fixed 16B column slice. Up to 32 edges via prefetched indices + 2-deep
// pipelined chunks of 4 row loads; deg>32 tail is a rare serial loop.
// Must be called by all 64 lanes of the wave (shfl participation).
static __device__ __forceinline__ void gather_node8(
    const ushort_t* __restrict__ tab, const int* __restrict__ csr_src, int e0,
    int e1, int sub8, int gbase, float2& c0, float2& c1, float2& c2,
    float2& c3) {
  const int off16 = sub8 << 3;  // ushort units: 16B per lane
  const int m = e1 - e0;
  // prefetch up to 32 indices (4 independent loads per lane)
  const int ir0 = (e0 + 0 + sub8 < e1) ? csr_src[e0 + 0 + sub8] : 0;
  const int ir1 = (e0 + 8 + sub8 < e1) ? csr_src[e0 + 8 + sub8] : 0;
  const int ir2 = (e0 + 16 + sub8 < e1) ? csr_src[e0 + 16 + sub8] : 0;
  const int ir3 = (e0 + 24 + sub8 < e1) ? csr_src[e0 + 24 + sub8] : 0;
  // wave-uniform chunk count from max degree (m uniform within group)
  int mm = m;
  mm = max(mm, __shfl_xor(mm, 8, 64));
  mm = max(mm, __shfl_xor(mm, 16, 64));
  mm = max(mm, __shfl_xor(mm, 32, 64));
  const int nch = __builtin_amdgcn_readfirstlane(min((mm + 3) >> 2, 8));
  const uint4 z4 = make_uint4(0, 0, 0, 0);
  uint4 A0, A1, A2, A3, B0, B1, B2, B3;
  if (nch > 0) {
    GLOAD4(A0, A1, A2, A3, ir0, 0, 0);
    if (nch > 1) GLOAD4(B0, B1, B2, B3, ir0, 4, 4);
    ACC4(A0, A1, A2, A3);
    if (nch > 1) {
      if (nch > 2) GLOAD4(A0, A1, A2, A3, ir1, 0, 8);
      ACC4(B0, B1, B2, B3);
      if (nch > 2) {
        if (nch > 3) GLOAD4(B0, B1, B2, B3, ir1, 4, 12);
        ACC4(A0, A1, A2, A3);
        if (nch > 3) {
          if (nch > 4) GLOAD4(A0, A1, A2, A3, ir2, 0, 16);
          ACC4(B0, B1, B2, B3);
          if (nch > 4) {
            if (nch > 5) GLOAD4(B0, B1, B2, B3, ir2, 4, 20);
            ACC4(A0, A1, A2, A3);
            if (nch > 5) {
              if (nch > 6) GLOAD4(A0, A1, A2, A3, ir3, 0, 24);
              ACC4(B0, B1, B2, B3);
              if (nch > 6) {
                if (nch > 7) GLOAD4(B0, B1, B2, B3, ir3, 4, 28);
                ACC4(A0, A1, A2, A3);
                if (nch > 7) ACC4(B0, B1, B2, B3);
              }
            }
          }
        }
      }
    }
  }
  // rare deg>32 tail (group-uniform loop, exec-masked per group)
  for (int eb = e0 + 32; eb < e1; ++eb) {
    const int ii = csr_src[eb];
    const uint4 tv = *(const uint4*)(tab + ((size_t)ii << 6) + off16);
    addrow(tv, c0, c1, c2, c3);
  }
}

// ---- K1: MFMA GEMM + residual for layer 1, plus gtail/off-tail init ----
__global__ __launch_bounds__(256) void gemm_res_mfma_kernel(
    const float* __restrict__ x, const float* __restrict__ W,
    const float* __restrict__ Wr, const float* __restrict__ br,
    ushort_t* __restrict__ xw, ushort_t* __restrict__ res, int n_nodes,
    int* __restrict__ gtail, int* __restrict__ off_tail, int n_edges) {
  if (blockIdx.x == 0) {
    if (threadIdx.x < NBMAX) gtail[threadIdx.x] = (int)threadIdx.x * CAP_PACK;
    if (threadIdx.x == 0) *off_tail = n_edges;  // csr_off[n_nodes]
  }
  const int lane = threadIdx.x & 63;
  const int wid = threadIdx.x >> 6;
  const int sub = lane & 15;
  const int q = lane >> 4;

  bf16x8 bW[4][2], bR[4][2];
#pragma unroll
  for (int t = 0; t < 4; ++t) {
#pragma unroll
    for (int s = 0; s < 2; ++s) {
      bf16x8 fw, fr;
#pragma unroll
      for (int j = 0; j < 8; ++j) {
        const int k = s * 32 + q * 8 + j;
        const int c = t * 16 + sub;
        fw[j] = (short)f2bf(W[k * D + c]);
        fr[j] = (short)f2bf(Wr[k * D + c]);
      }
      bW[t][s] = fw;
      bR[t][s] = fr;
    }
  }
  float brv[4];
#pragma unroll
  for (int t = 0; t < 4; ++t) brv[t] = br[t * 16 + sub];

  const int n_tiles = (n_nodes + 15) >> 4;
  const int wave_id = blockIdx.x * 4 + wid;
  const int n_waves = gridDim.x * 4;
  for (int tile = wave_id; tile < n_tiles; tile += n_waves) {
    const int n0 = tile << 4;
    const bool full = (n0 + 16 <= n_nodes);
    bf16x8 a0h, a0l, a1h, a1l;
    float v[16];
    if (full) {
      const float* xp = x + (size_t)(n0 + sub) * D + q * 8;
      *(float4*)(v + 0)  = *(const float4*)(xp);
      *(float4*)(v + 4)  = *(const float4*)(xp + 4);
      *(float4*)(v + 8)  = *(const float4*)(xp + 32);
      *(float4*)(v + 12) = *(const float4*)(xp + 36);
    } else {
      const bool ok = (n0 + sub) < n_nodes;
      const float* xp = x + (size_t)(n0 + sub) * D + q * 8;
#pragma unroll
      for (int j = 0; j < 8; ++j) {
        v[j] = ok ? xp[j] : 0.f;
        v[8 + j] = ok ? xp[32 + j] : 0.f;
      }
    }
#pragma unroll
    for (int j = 0; j < 8; ++j) {
      const ushort_t h0 = f2bf(v[j]);
      a0h[j] = (short)h0;
      a0l[j] = (short)f2bf(v[j] - bf2f(h0));
      const ushort_t h1 = f2bf(v[8 + j]);
      a1h[j] = (short)h1;
      a1l[j] = (short)f2bf(v[8 + j] - bf2f(h1));
    }
    floatx4 accW[4], accR[4];
#pragma unroll
    for (int t = 0; t < 4; ++t) {
      accW[t] = (floatx4){0.f, 0.f, 0.f, 0.f};
      accR[t] = (floatx4){0.f, 0.f, 0.f, 0.f};
    }
#pragma unroll
    for (int t = 0; t < 4; ++t) {
      accW[t] = __builtin_amdgcn_mfma_f32_16x16x32_bf16(a0h, bW[t][0], accW[t], 0, 0, 0);
      accW[t] = __builtin_amdgcn_mfma_f32_16x16x32_bf16(a0l, bW[t][0], accW[t], 0, 0, 0);
      accW[t] = __builtin_amdgcn_mfma_f32_16x16x32_bf16(a1h, bW[t][1], accW[t], 0, 0, 0);
      accW[t] = __builtin_amdgcn_mfma_f32_16x16x32_bf16(a1l, bW[t][1], accW[t], 0, 0, 0);
      accR[t] = __builtin_amdgcn_mfma_f32_16x16x32_bf16(a0h, bR[t][0], accR[t], 0, 0, 0);
      accR[t] = __builtin_amdgcn_mfma_f32_16x16x32_bf16(a0l, bR[t][0], accR[t], 0, 0, 0);
      accR[t] = __builtin_amdgcn_mfma_f32_16x16x32_bf16(a1h, bR[t][1], accR[t], 0, 0, 0);
      accR[t] = __builtin_amdgcn_mfma_f32_16x16x32_bf16(a1l, bR[t][1], accR[t], 0, 0, 0);
    }
    if (full) {
#pragma unroll
      for (int t = 0; t < 4; ++t) {
#pragma unroll
        for (int i = 0; i < 4; ++i) {
          const size_t r = (size_t)(n0 + q * 4 + i) * D + t * 16 + sub;
          xw[r] = f2bf(accW[t][i]);
          res[r] = f2bf(fmaxf(accR[t][i] + brv[t], 0.f));
        }
      }
    } else {
#pragma unroll
      for (int t = 0; t < 4; ++t) {
#pragma unroll
        for (int i = 0; i < 4; ++i) {
          const int rr = n0 + q * 4 + i;
          if (rr < n_nodes) {
            const size_t r = (size_t)rr * D + t * 16 + sub;
            xw[r] = f2bf(accW[t][i]);
            res[r] = f2bf(fmaxf(accR[t][i] + brv[t], 0.f));
          }
        }
      }
    }
  }
}

// ---- K2: chunk-local LDS sort by bucket, coalesced segment writes into
// per-bucket FIXED regions (b*CAP_PACK). Self-allocating via gtail atomics.
__global__ __launch_bounds__(256) void binpack_kernel(
    const int* __restrict__ src, const int* __restrict__ dst,
    int* __restrict__ gtail, unsigned* __restrict__ packed, int n_edges) {
  __shared__ int start[NBMAX], cur[NBMAX], gpos[NBMAX];
  __shared__ unsigned sorted[BCHUNK];
  __shared__ unsigned char bktid[BCHUNK];
  const int t = threadIdx.x;
  const int nchunk = (n_edges + BCHUNK - 1) / BCHUNK;
  for (int c = blockIdx.x; c < nchunk; c += gridDim.x) {
    cur[t] = 0;
    __syncthreads();
    const int e0 = c * BCHUNK;
    const int m = min(BCHUNK, n_edges - e0);
    int bk[16];
    unsigned pk[16];
#pragma unroll
    for (int k = 0; k < 16; ++k) {
      const int e = e0 + k * 256 + t;
      if (e < n_edges) {
        const int d = dst[e];
        const int s = src[e];
        bk[k] = d >> 9;
        pk[k] = ((unsigned)(d & 511) << 23) | (unsigned)s;
        atomicAdd(&cur[bk[k]], 1);
      } else {
        bk[k] = -1;
      }
    }
    __syncthreads();
    const int h = cur[t];
    start[t] = h;
    __syncthreads();
    for (int off = 1; off < NBMAX; off <<= 1) {
      const int v = (t >= off) ? start[t - off] : 0;
      __syncthreads();
      start[t] += v;
      __syncthreads();
    }
    const int excl = start[t] - h;
    __syncthreads();
    start[t] = excl;
    cur[t] = excl;
    __syncthreads();
#pragma unroll
    for (int k = 0; k < 16; ++k) {
      if (bk[k] >= 0) {
        const int pos = atomicAdd(&cur[bk[k]], 1);
        sorted[pos] = pk[k];
        bktid[pos] = (unsigned char)bk[k];
      }
    }
    __syncthreads();
    if (h > 0) gpos[t] = atomicAdd(&gtail[t], h);
    __syncthreads();
    for (int j = t; j < m; j += 256) {
      const int b = bktid[j];
      packed[gpos[b] + j - start[b]] = sorted[j];
    }
    __syncthreads();
  }
}

// ---- K3: one block per bucket. Redundant 196-entry LDS scan of gtail-derived
// counts -> exact bases; then LDS counting sort; coalesced csr_off/csr_src out.
__global__ __launch_bounds__(256) void bucket_csr_kernel(
    const unsigned* __restrict__ packed, const int* __restrict__ gtail,
    int* __restrict__ csr_off, int* __restrict__ csr_src, int n_nodes,
    int nbuckets) {
  __shared__ int scnt[NBMAX], sexc[NBMAX];
  __shared__ int sc[2][512];
  __shared__ int cur[512];
  __shared__ unsigned outbuf[CAP];
  const int b = blockIdx.x;
  const int t = threadIdx.x;
  // exact bucket bases from final gtails (count = gtail[b] - b*CAP_PACK)
  const int cb = (t < nbuckets) ? (gtail[t] - t * CAP_PACK) : 0;
  scnt[t] = cb;
  sexc[t] = cb;
  __syncthreads();
  for (int off = 1; off < NBMAX; off <<= 1) {
    const int v = (t >= off) ? sexc[t - off] : 0;
    __syncthreads();
    sexc[t] += v;
    __syncthreads();
  }
  sexc[t] -= scnt[t];  // exclusive
  __syncthreads();
  const int base = sexc[b];
  const int cntE = scnt[b];
  const unsigned* pk = packed + (size_t)b * CAP_PACK;

  const int n0 = b << 9;
  const int nn = min(512, n_nodes - n0);
  cur[t] = 0;
  cur[t + 256] = 0;
  __syncthreads();
  for (int i = t; i < cntE; i += 256) atomicAdd(&cur[pk[i] >> 23], 1);
  __syncthreads();
  const int h0 = cur[t];
  const int h1 = cur[t + 256];
  sc[0][t] = h0;
  sc[0][t + 256] = h1;
  __syncthreads();
  int pin = 0;
  for (int off = 1; off < 512; off <<= 1) {
    sc[1 - pin][t] = sc[pin][t] + ((t >= off) ? sc[pin][t - off] : 0);
    sc[1 - pin][t + 256] =
        sc[pin][t + 256] + ((t + 256 >= off) ? sc[pin][t + 256 - off] : 0);
    __syncthreads();
    pin ^= 1;
  }
  const int excl0 = sc[pin][t] - h0;
  const int excl1 = sc[pin][t + 256] - h1;
  if (t < nn) csr_off[n0 + t] = base + excl0;
  if (t + 256 < nn) csr_off[n0 + t + 256] = base + excl1;
  cur[t] = excl0;
  cur[t + 256] = excl1;
  __syncthreads();
  if (cntE <= CAP) {
    for (int i = t; i < cntE; i += 256) {
      const unsigned u = pk[i];
      const int pos = atomicAdd(&cur[u >> 23], 1);
      outbuf[pos] = u & 0x7FFFFFu;
    }
    __syncthreads();
    for (int j = t; j < cntE; j += 256) csr_src[base + j] = (int)outbuf[j];
  } else {  // overflow fallback
    for (int i = t; i < cntE; i += 256) {
      const unsigned u = pk[i];
      const int pos = atomicAdd(&cur[u >> 23], 1);
      csr_src[base + pos] = (int)(u & 0x7FFFFFu);
    }
  }
}

// ---- K4: fused gather1 + combine + gemm2, 32-row tiles ----
// Weights (W2,Wr2 fragments) and b1 live in LDS so the gather phase carries
// no persistent weight VGPRs.
__global__ __launch_bounds__(256, 6) void gather_gemm_kernel(
    const ushort_t* __restrict__ xw1, const ushort_t* __restrict__ res1,
    const float* __restrict__ b1v, const int* __restrict__ csr_off,
    const int* __restrict__ csr_src, const float* __restrict__ W2,
    const float* __restrict__ Wr2, const float* __restrict__ br2,
    ushort_t* __restrict__ xw2, ushort_t* __restrict__ res2, int n_nodes) {
  const int lane = threadIdx.x & 63;
  const int w = threadIdx.x >> 6;
  const int sub = lane & 15;  // gemm phase
  const int q = lane >> 4;    // gemm phase
  const int sub8 = lane & 7;  // gather phase
  const int g = lane >> 3;
  const int gbase = lane & 56;
  __shared__ float h_tile[32][68];
  __shared__ bf16x8 wfrag[2][8][64];  // [mat][(w*2+s)][lane], 16 KB
  __shared__ float b1s[64];

  // one-time loader: per-wave weight fragments -> LDS
#pragma unroll
  for (int s = 0; s < 2; ++s) {
    bf16x8 fw, fr;
#pragma unroll
    for (int j = 0; j < 8; ++j) {
      const int k = s * 32 + q * 8 + j;
      const int c = w * 16 + sub;
      fw[j] = (short)f2bf(W2[k * D + c]);
      fr[j] = (short)f2bf(Wr2[k * D + c]);
    }
    wfrag[0][w * 2 + s][lane] = fw;
    wfrag[1][w * 2 + s][lane] = fr;
  }
  if (threadIdx.x < 64) b1s[threadIdx.x] = b1v[threadIdx.x];
  const float brl2 = br2[w * 16 + sub];
  __syncthreads();

  const int n_tiles = (n_nodes + 31) >> 5;
  for (int tile = blockIdx.x; tile < n_tiles; tile += gridDim.x) {
    const int n0 = tile << 5;
    const int nb = n0 + w * 8;
    // 9 consecutive csr_off entries via lanes 0..8 (clamped; csr_off[n_nodes]
    // valid == n_edges, set by K1). Clamped nodes get m=0.
    const int offv = csr_off[min(nb + (lane < 9 ? lane : 8), n_nodes)];
    const int e0 = __shfl(offv, g, 64);
    const int e1 = __shfl(offv, g + 1, 64);
    float2 c0 = {0.f, 0.f}, c1 = {0.f, 0.f}, c2 = {0.f, 0.f}, c3 = {0.f, 0.f};
    gather_node8(xw1, csr_src, e0, e1, sub8, gbase, c0, c1, c2, c3);
    const int n = nb + g;
    const int row = (w << 3) + g;
    if (n < n_nodes) {
      const uint4 rv = *(const uint4*)(res1 + ((size_t)n << 6) + (sub8 << 3));
      const float2 bz0 = *(const float2*)(&b1s[sub8 * 8 + 0]);
      const float2 bz1 = *(const float2*)(&b1s[sub8 * 8 + 2]);
      const float2 bz2 = *(const float2*)(&b1s[sub8 * 8 + 4]);
      const float2 bz3 = *(const float2*)(&b1s[sub8 * 8 + 6]);
      float4 lo, hi;
      lo.x = fmaxf(c0.x + bz0.x, 0.f) + __uint_as_float(rv.x << 16);
      lo.y = fmaxf(c0.y + bz0.y, 0.f) + __uint_as_float(rv.x & 0xffff0000u);
      lo.z = fmaxf(c1.x + bz1.x, 0.f) + __uint_as_float(rv.y << 16);
      lo.w = fmaxf(c1.y + bz1.y, 0.f) + __uint_as_float(rv.y & 0xffff0000u);
      hi.x = fmaxf(c2.x + bz2.x, 0.f) + __uint_as_float(rv.z << 16);
      hi.y = fmaxf(c2.y + bz2.y, 0.f) + __uint_as_float(rv.z & 0xffff0000u);
      hi.z = fmaxf(c3.x + bz3.x, 0.f) + __uint_as_float(rv.w << 16);
      hi.w = fmaxf(c3.y + bz3.y, 0.f) + __uint_as_float(rv.w & 0xffff0000u);
      *(float4*)(&h_tile[row][sub8 * 8]) = lo;
      *(float4*)(&h_tile[row][sub8 * 8 + 4]) = hi;
    } else {
      *(float4*)(&h_tile[row][sub8 * 8]) = make_float4(0.f, 0.f, 0.f, 0.f);
      *(float4*)(&h_tile[row][sub8 * 8 + 4]) = make_float4(0.f, 0.f, 0.f, 0.f);
    }
    __syncthreads();
    // ---- gemm2: wave w computes cols w*16..+15 for both 16-row sub-tiles ----
#pragma unroll
    for (int st = 0; st < 2; ++st) {
      const float* hrow = &h_tile[st * 16 + sub][0];
      bf16x8 a0h, a0l, a1h, a1l;
      {
        const float4 p0 = *(const float4*)(hrow + q * 8);
        const float4 p1 = *(const float4*)(hrow + q * 8 + 4);
        const float vv[8] = {p0.x, p0.y, p0.z, p0.w, p1.x, p1.y, p1.z, p1.w};
#pragma unroll
        for (int j = 0; j < 8; ++j) {
          const ushort_t h0 = f2bf(vv[j]);
          a0h[j] = (short)h0;
          a0l[j] = (short)f2bf(vv[j] - bf2f(h0));
        }
      }
      {
        const float4 p2 = *(const float4*)(hrow + 32 + q * 8);
        const float4 p3 = *(const float4*)(hrow + 32 + q * 8 + 4);
        const float vv[8] = {p2.x, p2.y, p2.z, p2.w, p3.x, p3.y, p3.z, p3.w};
#pragma unroll
        for (int j = 0; j < 8; ++j) {
          const ushort_t h1 = f2bf(vv[j]);
          a1h[j] = (short)h1;
          a1l[j] = (short)f2bf(vv[j] - bf2f(h1));
        }
      }
      const bf16x8 w0 = wfrag[0][w * 2 + 0][lane];
      const bf16x8 w1 = wfrag[0][w * 2 + 1][lane];
      const bf16x8 r0 = wfrag[1][w * 2 + 0][lane];
      const bf16x8 r1 = wfrag[1][w * 2 + 1][lane];
      floatx4 accW = (floatx4){0.f, 0.f, 0.f, 0.f};
      floatx4 accR = (floatx4){0.f, 0.f, 0.f, 0.f};
      accW = __builtin_amdgcn_mfma_f32_16x16x32_bf16(a0h, w0, accW, 0, 0, 0);
      accW = __builtin_amdgcn_mfma_f32_16x16x32_bf16(a0l, w0, accW, 0, 0, 0);
      accW = __builtin_amdgcn_mfma_f32_16x16x32_bf16(a1h, w1, accW, 0, 0, 0);
      accW = __builtin_amdgcn_mfma_f32_16x16x32_bf16(a1l, w1, accW, 0, 0, 0);
      accR = __builtin_amdgcn_mfma_f32_16x16x32_bf16(a0h, r0, accR, 0, 0, 0);
      accR = __builtin_amdgcn_mfma_f32_16x16x32_bf16(a0l, r0, accR, 0, 0, 0);
      accR = __builtin_amdgcn_mfma_f32_16x16x32_bf16(a1h, r1, accR, 0, 0, 0);
      accR = __builtin_amdgcn_mfma_f32_16x16x32_bf16(a1l, r1, accR, 0, 0, 0);
#pragma unroll
      for (int i = 0; i < 4; ++i) {
        const int rr = n0 + st * 16 + q * 4 + i;
        if (rr < n_nodes) {
          const size_t r = (size_t)rr * D + w * 16 + sub;
          xw2[r] = f2bf(accW[i]);
          res2[r] = f2bf(fmaxf(accR[i] + brl2, 0.f));
        }
      }
    }
    __syncthreads();  // h_tile reused next tile
  }
}

// ---- K5: final gather + combine -> out (group-per-node gather) ----
// Plain launch_bounds: natural VGPR use (~64-70) — NEVER force below the
// pipeline's intrinsic need (round-3 lesson: forced 32 VGPR => 300MB of
// scratch spill traffic and a 1.6x kernel regression).
__global__ __launch_bounds__(256) void gather_combine_kernel(
    const ushort_t* __restrict__ xw, const ushort_t* __restrict__ res,
    const float* __restrict__ b, const int* __restrict__ csr_off,
    const int* __restrict__ csr_src, float* __restrict__ out, int n_nodes) {
  const int lane = threadIdx.x & 63;
  const int w = threadIdx.x >> 6;
  const int sub8 = lane & 7;
  const int g = lane >> 3;
  const int gbase = lane & 56;
  const int n_tiles = (n_nodes + 31) >> 5;
  for (int tile = blockIdx.x; tile < n_tiles; tile += gridDim.x) {
    const int nb = (tile << 5) + w * 8;
    const int offv = csr_off[min(nb + (lane < 9 ? lane : 8), n_nodes)];
    const int e0 = __shfl(offv, g, 64);
    const int e1 = __shfl(offv, g + 1, 64);
    float2 c0 = {0.f, 0.f}, c1 = {0.f, 0.f}, c2 = {0.f, 0.f}, c3 = {0.f, 0.f};
    gather_node8(xw, csr_src, e0, e1, sub8, gbase, c0, c1, c2, c3);
    const int n = nb + g;
    if (n < n_nodes) {
      const uint4 rv = *(const uint4*)(res + ((size_t)n << 6) + (sub8 << 3));
      const float4 blo = *(const float4*)(b + sub8 * 8);
      const float4 bhi = *(const float4*)(b + sub8 * 8 + 4);
      float4 lo, hi;
      lo.x = fmaxf(c0.x + blo.x, 0.f) + __uint_as_float(rv.x << 16);
      lo.y = fmaxf(c0.y + blo.y, 0.f) + __uint_as_float(rv.x & 0xffff0000u);
      lo.z = fmaxf(c1.x + blo.z, 0.f) + __uint_as_float(rv.y << 16);
      lo.w = fmaxf(c1.y + blo.w, 0.f) + __uint_as_float(rv.y & 0xffff0000u);
      hi.x = fmaxf(c2.x + bhi.x, 0.f) + __uint_as_float(rv.z << 16);
      hi.y = fmaxf(c2.y + bhi.y, 0.f) + __uint_as_float(rv.z & 0xffff0000u);
      hi.z = fmaxf(c3.x + bhi.z, 0.f) + __uint_as_float(rv.w << 16);
      hi.w = fmaxf(c3.y + bhi.w, 0.f) + __uint_as_float(rv.w & 0xffff0000u);
      *(float4*)(out + ((size_t)n << 6) + sub8 * 8) = lo;
      *(float4*)(out + ((size_t)n << 6) + sub8 * 8 + 4) = hi;
    }
  }
}

extern "C" void kernel_launch(void* const* d_in, const int* in_sizes, int n_in,
                              void* d_out, int out_size, void* d_ws, size_t ws_size,
                              hipStream_t stream) {
  const float* feats = (const float*)d_in[0];
  const float* W1  = (const float*)d_in[1];
  const float* b1  = (const float*)d_in[2];
  const float* Wr1 = (const float*)d_in[3];
  const float* br1 = (const float*)d_in[4];
  const float* W2  = (const float*)d_in[5];
  const float* b2  = (const float*)d_in[6];
  const float* Wr2 = (const float*)d_in[7];
  const float* br2 = (const float*)d_in[8];
  const int* src = (const int*)d_in[9];
  const int* dst = (const int*)d_in[10];
  const int n_nodes = in_sizes[0] / D;
  const int n_edges = in_sizes[9];
  float* out = (float*)d_out;

  const int nbuckets = (n_nodes + 511) >> 9;  // 196 for N=100k

  // workspace layout (~70 MB)
  ushort_t* xw1 = (ushort_t*)d_ws;                     // n_nodes*D bf16
  ushort_t* res1 = xw1 + (size_t)n_nodes * D;
  ushort_t* xw2 = res1 + (size_t)n_nodes * D;
  ushort_t* res2 = xw2 + (size_t)n_nodes * D;
  int* csr_off = (int*)(res2 + (size_t)n_nodes * D);   // n_nodes+1
  int* csr_src = csr_off + (n_nodes + 1);              // n_edges
  int* gtail = csr_src + n_edges;                      // NBMAX
  unsigned* packed = (unsigned*)(gtail + NBMAX);       // NBMAX*CAP_PACK

  const int tiles32 = (n_nodes + 31) / 32;             // 3125 for N=100k
  const int gblocks = tiles32 < 16384 ? tiles32 : 16384;
  const int nchunk = (n_edges + BCHUNK - 1) / BCHUNK;
  const int pblocks = nchunk < 1024 ? nchunk : 1024;
  dim3 blk(256);

  // K1: layer-1 dual GEMM (also inits gtail + csr_off tail for the CSR build)
  gemm_res_mfma_kernel<<<1024, blk, 0, stream>>>(
      feats, W1, Wr1, br1, xw1, res1, n_nodes, gtail, csr_off + n_nodes, n_edges);
  // K2: bucket the edge list (self-allocating fixed regions)
  binpack_kernel<<<pblocks, blk, 0, stream>>>(src, dst, gtail, packed, n_edges);
  // K3: per-bucket counting sort -> csr_off, csr_src
  bucket_csr_kernel<<<nbuckets, blk, 0, stream>>>(packed, gtail, csr_off,
                                                  csr_src, n_nodes, nbuckets);
  // K4: gather1 + combine + layer-2 dual GEMM (h1 stays in LDS)
  gather_gemm_kernel<<<gblocks, blk, 0, stream>>>(
      xw1, res1, b1, csr_off, csr_src, W2, Wr2, br2, xw2, res2, n_nodes);
  // K5: final gather + combine -> out
  gather_combine_kernel<<<gblocks, blk, 0, stream>>>(
      xw2, res2, b2, csr_off, csr_src, out, n_nodes);
}

// Round 5
// 228.119 us; speedup vs baseline: 1.2915x; 1.1158x over previous
//
#include <hip/hip_runtime.h>

#define D 64
#define NBMAX 256       // bucket count padded to 256 (real NB = ceil(N/512) = 196)
#define BCHUNK 4096     // edges per binpack block-iteration
#define CAP 8192        // LDS staging cap in bucket_csr (mean 6122, +26 sigma)
#define CAP_PACK 12288  // fixed per-bucket region in packed[] (self-allocating)

typedef unsigned short ushort_t;
typedef __attribute__((ext_vector_type(8))) short bf16x8;
typedef __attribute__((ext_vector_type(4))) float floatx4;

static __device__ __forceinline__ ushort_t f2bf(float x) {
  unsigned u = __float_as_uint(x);
  unsigned r = (u + 0x7FFF + ((u >> 16) & 1)) >> 16;  // RNE
  return (ushort_t)r;
}
static __device__ __forceinline__ float bf2f(ushort_t u) {
  return __uint_as_float(((unsigned)u) << 16);
}

// Accumulate one 16B (8 x bf16) row slice into 4 float2 accumulators.
static __device__ __forceinline__ void addrow(const uint4 v, float2& a0,
                                              float2& a1, float2& a2,
                                              float2& a3) {
  a0.x += __uint_as_float(v.x << 16);
  a0.y += __uint_as_float(v.x & 0xffff0000u);
  a1.x += __uint_as_float(v.y << 16);
  a1.y += __uint_as_float(v.y & 0xffff0000u);
  a2.x += __uint_as_float(v.z << 16);
  a2.y += __uint_as_float(v.z & 0xffff0000u);
  a3.x += __uint_as_float(v.w << 16);
  a3.y += __uint_as_float(v.w & 0xffff0000u);
}

// Load 4 row-slices (chunk CB..CB+3 of this group's edge list). Masked slots
// return zeros so accumulation is unconditional.
#define GLOAD4(T0, T1, T2, T3, IR, OFF, CB)                                    \
  do {                                                                         \
    const int s0_ = __shfl((IR), gbase + (OFF) + 0, 64);                       \
    const int s1_ = __shfl((IR), gbase + (OFF) + 1, 64);                       \
    const int s2_ = __shfl((IR), gbase + (OFF) + 2, 64);                       \
    const int s3_ = __shfl((IR), gbase + (OFF) + 3, 64);                       \
    T0 = ((CB) + 0 < m) ? *(const uint4*)(tab + ((size_t)s0_ << 6) + off16)    \
                        : z4;                                                  \
    T1 = ((CB) + 1 < m) ? *(const uint4*)(tab + ((size_t)s1_ << 6) + off16)    \
                        : z4;                                                  \
    T2 = ((CB) + 2 < m) ? *(const uint4*)(tab + ((size_t)s2_ << 6) + off16)    \
                        : z4;                                                  \
    T3 = ((CB) + 3 < m) ? *(const uint4*)(tab + ((size_t)s3_ << 6) + off16)    \
                        : z4;                                                  \
  } while (0)

#define ACC4(T0, T1, T2, T3)    \
  do {                          \
    addrow(T0, c0, c1, c2, c3); \
    addrow(T1, c0, c1, c2, c3); \
    addrow(T2, c0, c1, c2, c3); \
    addrow(T3, c0, c1, c2, c3); \
  } while (0)

// Group-per-node gather: 8-lane group owns node (e0..e1), each lane owns a
// fixed 16B column slice. Up to 32 edges via prefetched indices + 2-deep
// pipelined chunks of 4 row loads; deg>32 tail is a rare serial loop.
// Must be called by all 64 lanes of the wave (shfl participation).
static __device__ __forceinline__ void gather_node8(
    const ushort_t* __restrict__ tab, const int* __restrict__ csr_src, int e0,
    int e1, int sub8, int gbase, float2& c0, float2& c1, float2& c2,
    float2& c3) {
  const int off16 = sub8 << 3;  // ushort units: 16B per lane
  const int m = e1 - e0;
  // prefetch up to 32 indices (4 independent loads per lane)
  const int ir0 = (e0 + 0 + sub8 < e1) ? csr_src[e0 + 0 + sub8] : 0;
  const int ir1 = (e0 + 8 + sub8 < e1) ? csr_src[e0 + 8 + sub8] : 0;
  const int ir2 = (e0 + 16 + sub8 < e1) ? csr_src[e0 + 16 + sub8] : 0;
  const int ir3 = (e0 + 24 + sub8 < e1) ? csr_src[e0 + 24 + sub8] : 0;
  // wave-uniform chunk count from max degree (m uniform within group)
  int mm = m;
  mm = max(mm, __shfl_xor(mm, 8, 64));
  mm = max(mm, __shfl_xor(mm, 16, 64));
  mm = max(mm, __shfl_xor(mm, 32, 64));
  const int nch = __builtin_amdgcn_readfirstlane(min((mm + 3) >> 2, 8));
  const uint4 z4 = make_uint4(0, 0, 0, 0);
  uint4 A0, A1, A2, A3, B0, B1, B2, B3;
  if (nch > 0) {
    GLOAD4(A0, A1, A2, A3, ir0, 0, 0);
    if (nch > 1) GLOAD4(B0, B1, B2, B3, ir0, 4, 4);
    ACC4(A0, A1, A2, A3);
    if (nch > 1) {
      if (nch > 2) GLOAD4(A0, A1, A2, A3, ir1, 0, 8);
      ACC4(B0, B1, B2, B3);
      if (nch > 2) {
        if (nch > 3) GLOAD4(B0, B1, B2, B3, ir1, 4, 12);
        ACC4(A0, A1, A2, A3);
        if (nch > 3) {
          if (nch > 4) GLOAD4(A0, A1, A2, A3, ir2, 0, 16);
          ACC4(B0, B1, B2, B3);
          if (nch > 4) {
            if (nch > 5) GLOAD4(B0, B1, B2, B3, ir2, 4, 20);
            ACC4(A0, A1, A2, A3);
            if (nch > 5) {
              if (nch > 6) GLOAD4(A0, A1, A2, A3, ir3, 0, 24);
              ACC4(B0, B1, B2, B3);
              if (nch > 6) {
                if (nch > 7) GLOAD4(B0, B1, B2, B3, ir3, 4, 28);
                ACC4(A0, A1, A2, A3);
                if (nch > 7) ACC4(B0, B1, B2, B3);
              }
            }
          }
        }
      }
    }
  }
  // rare deg>32 tail (group-uniform loop, exec-masked per group)
  for (int eb = e0 + 32; eb < e1; ++eb) {
    const int ii = csr_src[eb];
    const uint4 tv = *(const uint4*)(tab + ((size_t)ii << 6) + off16);
    addrow(tv, c0, c1, c2, c3);
  }
}

// ---- K12: FUSED layer-1 dual GEMM + edge binpack ----
// Blocks [0,pblocks): binpack (chunk-local LDS sort -> per-bucket fixed
// regions; gtail is pre-zeroed by hipMemsetAsync, base t*CAP_PACK added here).
// Blocks [pblocks, pblocks+1024): layer-1 MFMA GEMM + residual.
// The two halves touch disjoint data; fusing removes one dispatch boundary.
__global__ __launch_bounds__(256) void prep_kernel(
    const float* __restrict__ x, const float* __restrict__ W,
    const float* __restrict__ Wr, const float* __restrict__ br,
    ushort_t* __restrict__ xw, ushort_t* __restrict__ res, int n_nodes,
    const int* __restrict__ src, const int* __restrict__ dst,
    int* __restrict__ gtail, unsigned* __restrict__ packed, int n_edges,
    int pblocks) {
  __shared__ int start[NBMAX], cur[NBMAX], gpos[NBMAX];
  __shared__ unsigned sorted[BCHUNK];
  __shared__ unsigned char bktid[BCHUNK];
  if ((int)blockIdx.x < pblocks) {
    // ================= binpack half =================
    const int t = threadIdx.x;
    const int nchunk = (n_edges + BCHUNK - 1) / BCHUNK;
    for (int c = blockIdx.x; c < nchunk; c += pblocks) {
      cur[t] = 0;
      __syncthreads();
      const int e0 = c * BCHUNK;
      const int m = min(BCHUNK, n_edges - e0);
      int bk[16];
      unsigned pk[16];
#pragma unroll
      for (int k = 0; k < 16; ++k) {
        const int e = e0 + k * 256 + t;
        if (e < n_edges) {
          const int d = dst[e];
          const int s = src[e];
          bk[k] = d >> 9;
          pk[k] = ((unsigned)(d & 511) << 23) | (unsigned)s;
          atomicAdd(&cur[bk[k]], 1);
        } else {
          bk[k] = -1;
        }
      }
      __syncthreads();
      const int h = cur[t];
      start[t] = h;
      __syncthreads();
      for (int off = 1; off < NBMAX; off <<= 1) {
        const int v = (t >= off) ? start[t - off] : 0;
        __syncthreads();
        start[t] += v;
        __syncthreads();
      }
      const int excl = start[t] - h;
      __syncthreads();
      start[t] = excl;
      cur[t] = excl;
      __syncthreads();
#pragma unroll
      for (int k = 0; k < 16; ++k) {
        if (bk[k] >= 0) {
          const int pos = atomicAdd(&cur[bk[k]], 1);
          sorted[pos] = pk[k];
          bktid[pos] = (unsigned char)bk[k];
        }
      }
      __syncthreads();
      if (h > 0) gpos[t] = t * CAP_PACK + atomicAdd(&gtail[t], h);
      __syncthreads();
      for (int j = t; j < m; j += 256) {
        const int b = bktid[j];
        packed[gpos[b] + j - start[b]] = sorted[j];
      }
      __syncthreads();
    }
    return;
  }
  // ================= layer-1 GEMM half =================
  const int lane = threadIdx.x & 63;
  const int wid = threadIdx.x >> 6;
  const int sub = lane & 15;
  const int q = lane >> 4;

  bf16x8 bW[4][2], bR[4][2];
#pragma unroll
  for (int t = 0; t < 4; ++t) {
#pragma unroll
    for (int s = 0; s < 2; ++s) {
      bf16x8 fw, fr;
#pragma unroll
      for (int j = 0; j < 8; ++j) {
        const int k = s * 32 + q * 8 + j;
        const int c = t * 16 + sub;
        fw[j] = (short)f2bf(W[k * D + c]);
        fr[j] = (short)f2bf(Wr[k * D + c]);
      }
      bW[t][s] = fw;
      bR[t][s] = fr;
    }
  }
  float brv[4];
#pragma unroll
  for (int t = 0; t < 4; ++t) brv[t] = br[t * 16 + sub];

  const int gb = (int)gridDim.x - pblocks;
  const int n_tiles = (n_nodes + 15) >> 4;
  const int wave_id = ((int)blockIdx.x - pblocks) * 4 + wid;
  const int n_waves = gb * 4;
  for (int tile = wave_id; tile < n_tiles; tile += n_waves) {
    const int n0 = tile << 4;
    const bool full = (n0 + 16 <= n_nodes);
    bf16x8 a0h, a0l, a1h, a1l;
    float v[16];
    if (full) {
      const float* xp = x + (size_t)(n0 + sub) * D + q * 8;
      *(float4*)(v + 0)  = *(const float4*)(xp);
      *(float4*)(v + 4)  = *(const float4*)(xp + 4);
      *(float4*)(v + 8)  = *(const float4*)(xp + 32);
      *(float4*)(v + 12) = *(const float4*)(xp + 36);
    } else {
      const bool ok = (n0 + sub) < n_nodes;
      const float* xp = x + (size_t)(n0 + sub) * D + q * 8;
#pragma unroll
      for (int j = 0; j < 8; ++j) {
        v[j] = ok ? xp[j] : 0.f;
        v[8 + j] = ok ? xp[32 + j] : 0.f;
      }
    }
#pragma unroll
    for (int j = 0; j < 8; ++j) {
      const ushort_t h0 = f2bf(v[j]);
      a0h[j] = (short)h0;
      a0l[j] = (short)f2bf(v[j] - bf2f(h0));
      const ushort_t h1 = f2bf(v[8 + j]);
      a1h[j] = (short)h1;
      a1l[j] = (short)f2bf(v[8 + j] - bf2f(h1));
    }
    floatx4 accW[4], accR[4];
#pragma unroll
    for (int t = 0; t < 4; ++t) {
      accW[t] = (floatx4){0.f, 0.f, 0.f, 0.f};
      accR[t] = (floatx4){0.f, 0.f, 0.f, 0.f};
    }
#pragma unroll
    for (int t = 0; t < 4; ++t) {
      accW[t] = __builtin_amdgcn_mfma_f32_16x16x32_bf16(a0h, bW[t][0], accW[t], 0, 0, 0);
      accW[t] = __builtin_amdgcn_mfma_f32_16x16x32_bf16(a0l, bW[t][0], accW[t], 0, 0, 0);
      accW[t] = __builtin_amdgcn_mfma_f32_16x16x32_bf16(a1h, bW[t][1], accW[t], 0, 0, 0);
      accW[t] = __builtin_amdgcn_mfma_f32_16x16x32_bf16(a1l, bW[t][1], accW[t], 0, 0, 0);
      accR[t] = __builtin_amdgcn_mfma_f32_16x16x32_bf16(a0h, bR[t][0], accR[t], 0, 0, 0);
      accR[t] = __builtin_amdgcn_mfma_f32_16x16x32_bf16(a0l, bR[t][0], accR[t], 0, 0, 0);
      accR[t] = __builtin_amdgcn_mfma_f32_16x16x32_bf16(a1h, bR[t][1], accR[t], 0, 0, 0);
      accR[t] = __builtin_amdgcn_mfma_f32_16x16x32_bf16(a1l, bR[t][1], accR[t], 0, 0, 0);
    }
    if (full) {
#pragma unroll
      for (int t = 0; t < 4; ++t) {
#pragma unroll
        for (int i = 0; i < 4; ++i) {
          const size_t r = (size_t)(n0 + q * 4 + i) * D + t * 16 + sub;
          xw[r] = f2bf(accW[t][i]);
          res[r] = f2bf(fmaxf(accR[t][i] + brv[t], 0.f));
        }
      }
    } else {
#pragma unroll
      for (int t = 0; t < 4; ++t) {
#pragma unroll
        for (int i = 0; i < 4; ++i) {
          const int rr = n0 + q * 4 + i;
          if (rr < n_nodes) {
            const size_t r = (size_t)rr * D + t * 16 + sub;
            xw[r] = f2bf(accW[t][i]);
            res[r] = f2bf(fmaxf(accR[t][i] + brv[t], 0.f));
          }
        }
      }
    }
  }
}

// ---- K3: one block per bucket. Redundant 196-entry LDS scan of gtail counts
// -> exact bases; then LDS counting sort; coalesced csr_off/csr_src out.
// Also writes the csr_off[n_nodes] = n_edges tail (block 0).
__global__ __launch_bounds__(256) void bucket_csr_kernel(
    const unsigned* __restrict__ packed, const int* __restrict__ gtail,
    int* __restrict__ csr_off, int* __restrict__ csr_src, int n_nodes,
    int nbuckets, int n_edges) {
  __shared__ int scnt[NBMAX], sexc[NBMAX];
  __shared__ int sc[2][512];
  __shared__ int cur[512];
  __shared__ unsigned outbuf[CAP];
  const int b = blockIdx.x;
  const int t = threadIdx.x;
  if (b == 0 && t == 0) csr_off[n_nodes] = n_edges;
  // bucket counts directly from gtail (zero-based since memset)
  const int cb = (t < nbuckets) ? gtail[t] : 0;
  scnt[t] = cb;
  sexc[t] = cb;
  __syncthreads();
  for (int off = 1; off < NBMAX; off <<= 1) {
    const int v = (t >= off) ? sexc[t - off] : 0;
    __syncthreads();
    sexc[t] += v;
    __syncthreads();
  }
  sexc[t] -= scnt[t];  // exclusive
  __syncthreads();
  const int base = sexc[b];
  const int cntE = scnt[b];
  const unsigned* pk = packed + (size_t)b * CAP_PACK;

  const int n0 = b << 9;
  const int nn = min(512, n_nodes - n0);
  cur[t] = 0;
  cur[t + 256] = 0;
  __syncthreads();
  for (int i = t; i < cntE; i += 256) atomicAdd(&cur[pk[i] >> 23], 1);
  __syncthreads();
  const int h0 = cur[t];
  const int h1 = cur[t + 256];
  sc[0][t] = h0;
  sc[0][t + 256] = h1;
  __syncthreads();
  int pin = 0;
  for (int off = 1; off < 512; off <<= 1) {
    sc[1 - pin][t] = sc[pin][t] + ((t >= off) ? sc[pin][t - off] : 0);
    sc[1 - pin][t + 256] =
        sc[pin][t + 256] + ((t + 256 >= off) ? sc[pin][t + 256 - off] : 0);
    __syncthreads();
    pin ^= 1;
  }
  const int excl0 = sc[pin][t] - h0;
  const int excl1 = sc[pin][t + 256] - h1;
  if (t < nn) csr_off[n0 + t] = base + excl0;
  if (t + 256 < nn) csr_off[n0 + t + 256] = base + excl1;
  cur[t] = excl0;
  cur[t + 256] = excl1;
  __syncthreads();
  if (cntE <= CAP) {
    for (int i = t; i < cntE; i += 256) {
      const unsigned u = pk[i];
      const int pos = atomicAdd(&cur[u >> 23], 1);
      outbuf[pos] = u & 0x7FFFFFu;
    }
    __syncthreads();
    for (int j = t; j < cntE; j += 256) csr_src[base + j] = (int)outbuf[j];
  } else {  // overflow fallback
    for (int i = t; i < cntE; i += 256) {
      const unsigned u = pk[i];
      const int pos = atomicAdd(&cur[u >> 23], 1);
      csr_src[base + pos] = (int)(u & 0x7FFFFFu);
    }
  }
}

// ---- K4: fused gather1 + combine + gemm2, 32-row tiles ----
// Weights (W2,Wr2 fragments) and b1 live in LDS so the gather phase carries
// no persistent weight VGPRs. PLAIN launch bounds: forcing a min-waves clause
// (rounds 3/4) makes the allocator clamp the frame and spill the gather
// pipeline to scratch (+70MB HBM traffic). Natural allocation only.
__global__ __launch_bounds__(256) void gather_gemm_kernel(
    const ushort_t* __restrict__ xw1, const ushort_t* __restrict__ res1,
    const float* __restrict__ b1v, const int* __restrict__ csr_off,
    const int* __restrict__ csr_src, const float* __restrict__ W2,
    const float* __restrict__ Wr2, const float* __restrict__ br2,
    ushort_t* __restrict__ xw2, ushort_t* __restrict__ res2, int n_nodes) {
  const int lane = threadIdx.x & 63;
  const int w = threadIdx.x >> 6;
  const int sub = lane & 15;  // gemm phase
  const int q = lane >> 4;    // gemm phase
  const int sub8 = lane & 7;  // gather phase
  const int g = lane >> 3;
  const int gbase = lane & 56;
  __shared__ float h_tile[32][68];
  __shared__ bf16x8 wfrag[2][8][64];  // [mat][(w*2+s)][lane], 16 KB
  __shared__ float b1s[64];

  // one-time loader: per-wave weight fragments -> LDS
#pragma unroll
  for (int s = 0; s < 2; ++s) {
    bf16x8 fw, fr;
#pragma unroll
    for (int j = 0; j < 8; ++j) {
      const int k = s * 32 + q * 8 + j;
      const int c = w * 16 + sub;
      fw[j] = (short)f2bf(W2[k * D + c]);
      fr[j] = (short)f2bf(Wr2[k * D + c]);
    }
    wfrag[0][w * 2 + s][lane] = fw;
    wfrag[1][w * 2 + s][lane] = fr;
  }
  if (threadIdx.x < 64) b1s[threadIdx.x] = b1v[threadIdx.x];
  const float brl2 = br2[w * 16 + sub];
  __syncthreads();

  const int n_tiles = (n_nodes + 31) >> 5;
  for (int tile = blockIdx.x; tile < n_tiles; tile += gridDim.x) {
    const int n0 = tile << 5;
    const int nb = n0 + w * 8;
    // 9 consecutive csr_off entries via lanes 0..8 (clamped; csr_off[n_nodes]
    // valid == n_edges, set by K3). Clamped nodes get m=0.
    const int offv = csr_off[min(nb + (lane < 9 ? lane : 8), n_nodes)];
    const int e0 = __shfl(offv, g, 64);
    const int e1 = __shfl(offv, g + 1, 64);
    float2 c0 = {0.f, 0.f}, c1 = {0.f, 0.f}, c2 = {0.f, 0.f}, c3 = {0.f, 0.f};
    gather_node8(xw1, csr_src, e0, e1, sub8, gbase, c0, c1, c2, c3);
    const int n = nb + g;
    const int row = (w << 3) + g;
    if (n < n_nodes) {
      const uint4 rv = *(const uint4*)(res1 + ((size_t)n << 6) + (sub8 << 3));
      const float2 bz0 = *(const float2*)(&b1s[sub8 * 8 + 0]);
      const float2 bz1 = *(const float2*)(&b1s[sub8 * 8 + 2]);
      const float2 bz2 = *(const float2*)(&b1s[sub8 * 8 + 4]);
      const float2 bz3 = *(const float2*)(&b1s[sub8 * 8 + 6]);
      float4 lo, hi;
      lo.x = fmaxf(c0.x + bz0.x, 0.f) + __uint_as_float(rv.x << 16);
      lo.y = fmaxf(c0.y + bz0.y, 0.f) + __uint_as_float(rv.x & 0xffff0000u);
      lo.z = fmaxf(c1.x + bz1.x, 0.f) + __uint_as_float(rv.y << 16);
      lo.w = fmaxf(c1.y + bz1.y, 0.f) + __uint_as_float(rv.y & 0xffff0000u);
      hi.x = fmaxf(c2.x + bz2.x, 0.f) + __uint_as_float(rv.z << 16);
      hi.y = fmaxf(c2.y + bz2.y, 0.f) + __uint_as_float(rv.z & 0xffff0000u);
      hi.z = fmaxf(c3.x + bz3.x, 0.f) + __uint_as_float(rv.w << 16);
      hi.w = fmaxf(c3.y + bz3.y, 0.f) + __uint_as_float(rv.w & 0xffff0000u);
      *(float4*)(&h_tile[row][sub8 * 8]) = lo;
      *(float4*)(&h_tile[row][sub8 * 8 + 4]) = hi;
    } else {
      *(float4*)(&h_tile[row][sub8 * 8]) = make_float4(0.f, 0.f, 0.f, 0.f);
      *(float4*)(&h_tile[row][sub8 * 8 + 4]) = make_float4(0.f, 0.f, 0.f, 0.f);
    }
    __syncthreads();
    // ---- gemm2: wave w computes cols w*16..+15 for both 16-row sub-tiles ----
#pragma unroll
    for (int st = 0; st < 2; ++st) {
      const float* hrow = &h_tile[st * 16 + sub][0];
      bf16x8 a0h, a0l, a1h, a1l;
      {
        const float4 p0 = *(const float4*)(hrow + q * 8);
        const float4 p1 = *(const float4*)(hrow + q * 8 + 4);
        const float vv[8] = {p0.x, p0.y, p0.z, p0.w, p1.x, p1.y, p1.z, p1.w};
#pragma unroll
        for (int j = 0; j < 8; ++j) {
          const ushort_t h0 = f2bf(vv[j]);
          a0h[j] = (short)h0;
          a0l[j] = (short)f2bf(vv[j] - bf2f(h0));
        }
      }
      {
        const float4 p2 = *(const float4*)(hrow + 32 + q * 8);
        const float4 p3 = *(const float4*)(hrow + 32 + q * 8 + 4);
        const float vv[8] = {p2.x, p2.y, p2.z, p2.w, p3.x, p3.y, p3.z, p3.w};
#pragma unroll
        for (int j = 0; j < 8; ++j) {
          const ushort_t h1 = f2bf(vv[j]);
          a1h[j] = (short)h1;
          a1l[j] = (short)f2bf(vv[j] - bf2f(h1));
        }
      }
      const bf16x8 w0 = wfrag[0][w * 2 + 0][lane];
      const bf16x8 w1 = wfrag[0][w * 2 + 1][lane];
      const bf16x8 r0 = wfrag[1][w * 2 + 0][lane];
      const bf16x8 r1 = wfrag[1][w * 2 + 1][lane];
      floatx4 accW = (floatx4){0.f, 0.f, 0.f, 0.f};
      floatx4 accR = (floatx4){0.f, 0.f, 0.f, 0.f};
      accW = __builtin_amdgcn_mfma_f32_16x16x32_bf16(a0h, w0, accW, 0, 0, 0);
      accW = __builtin_amdgcn_mfma_f32_16x16x32_bf16(a0l, w0, accW, 0, 0, 0);
      accW = __builtin_amdgcn_mfma_f32_16x16x32_bf16(a1h, w1, accW, 0, 0, 0);
      accW = __builtin_amdgcn_mfma_f32_16x16x32_bf16(a1l, w1, accW, 0, 0, 0);
      accR = __builtin_amdgcn_mfma_f32_16x16x32_bf16(a0h, r0, accR, 0, 0, 0);
      accR = __builtin_amdgcn_mfma_f32_16x16x32_bf16(a0l, r0, accR, 0, 0, 0);
      accR = __builtin_amdgcn_mfma_f32_16x16x32_bf16(a1h, r1, accR, 0, 0, 0);
      accR = __builtin_amdgcn_mfma_f32_16x16x32_bf16(a1l, r1, accR, 0, 0, 0);
#pragma unroll
      for (int i = 0; i < 4; ++i) {
        const int rr = n0 + st * 16 + q * 4 + i;
        if (rr < n_nodes) {
          const size_t r = (size_t)rr * D + w * 16 + sub;
          xw2[r] = f2bf(accW[i]);
          res2[r] = f2bf(fmaxf(accR[i] + brl2, 0.f));
        }
      }
    }
    __syncthreads();  // h_tile reused next tile
  }
}

// ---- K5: final gather + combine -> out (group-per-node gather) ----
// Plain launch_bounds: natural VGPR use — never force below the pipeline's
// intrinsic need (round-3 lesson: forced caps => scratch spill => 1.6x slow).
__global__ __launch_bounds__(256) void gather_combine_kernel(
    const ushort_t* __restrict__ xw, const ushort_t* __restrict__ res,
    const float* __restrict__ b, const int* __restrict__ csr_off,
    const int* __restrict__ csr_src, float* __restrict__ out, int n_nodes) {
  const int lane = threadIdx.x & 63;
  const int w = threadIdx.x >> 6;
  const int sub8 = lane & 7;
  const int g = lane >> 3;
  const int gbase = lane & 56;
  const int n_tiles = (n_nodes + 31) >> 5;
  for (int tile = blockIdx.x; tile < n_tiles; tile += gridDim.x) {
    const int nb = (tile << 5) + w * 8;
    const int offv = csr_off[min(nb + (lane < 9 ? lane : 8), n_nodes)];
    const int e0 = __shfl(offv, g, 64);
    const int e1 = __shfl(offv, g + 1, 64);
    float2 c0 = {0.f, 0.f}, c1 = {0.f, 0.f}, c2 = {0.f, 0.f}, c3 = {0.f, 0.f};
    gather_node8(xw, csr_src, e0, e1, sub8, gbase, c0, c1, c2, c3);
    const int n = nb + g;
    if (n < n_nodes) {
      const uint4 rv = *(const uint4*)(res + ((size_t)n << 6) + (sub8 << 3));
      const float4 blo = *(const float4*)(b + sub8 * 8);
      const float4 bhi = *(const float4*)(b + sub8 * 8 + 4);
      float4 lo, hi;
      lo.x = fmaxf(c0.x + blo.x, 0.f) + __uint_as_float(rv.x << 16);
      lo.y = fmaxf(c0.y + blo.y, 0.f) + __uint_as_float(rv.x & 0xffff0000u);
      lo.z = fmaxf(c1.x + blo.z, 0.f) + __uint_as_float(rv.y << 16);
      lo.w = fmaxf(c1.y + blo.w, 0.f) + __uint_as_float(rv.y & 0xffff0000u);
      hi.x = fmaxf(c2.x + bhi.x, 0.f) + __uint_as_float(rv.z << 16);
      hi.y = fmaxf(c2.y + bhi.y, 0.f) + __uint_as_float(rv.z & 0xffff0000u);
      hi.z = fmaxf(c3.x + bhi.z, 0.f) + __uint_as_float(rv.w << 16);
      hi.w = fmaxf(c3.y + bhi.w, 0.f) + __uint_as_float(rv.w & 0xffff0000u);
      *(float4*)(out + ((size_t)n << 6) + sub8 * 8) = lo;
      *(float4*)(out + ((size_t)n << 6) + sub8 * 8 + 4) = hi;
    }
  }
}

extern "C" void kernel_launch(void* const* d_in, const int* in_sizes, int n_in,
                              void* d_out, int out_size, void* d_ws, size_t ws_size,
                              hipStream_t stream) {
  const float* feats = (const float*)d_in[0];
  const float* W1  = (const float*)d_in[1];
  const float* b1  = (const float*)d_in[2];
  const float* Wr1 = (const float*)d_in[3];
  const float* br1 = (const float*)d_in[4];
  const float* W2  = (const float*)d_in[5];
  const float* b2  = (const float*)d_in[6];
  const float* Wr2 = (const float*)d_in[7];
  const float* br2 = (const float*)d_in[8];
  const int* src = (const int*)d_in[9];
  const int* dst = (const int*)d_in[10];
  const int n_nodes = in_sizes[0] / D;
  const int n_edges = in_sizes[9];
  float* out = (float*)d_out;

  const int nbuckets = (n_nodes + 511) >> 9;  // 196 for N=100k

  // workspace layout (~70 MB)
  ushort_t* xw1 = (ushort_t*)d_ws;                     // n_nodes*D bf16
  ushort_t* res1 = xw1 + (size_t)n_nodes * D;
  ushort_t* xw2 = res1 + (size_t)n_nodes * D;
  ushort_t* res2 = xw2 + (size_t)n_nodes * D;
  int* csr_off = (int*)(res2 + (size_t)n_nodes * D);   // n_nodes+1
  int* csr_src = csr_off + (n_nodes + 1);              // n_edges
  int* gtail = csr_src + n_edges;                      // NBMAX
  unsigned* packed = (unsigned*)(gtail + NBMAX);       // NBMAX*CAP_PACK

  const int tiles32 = (n_nodes + 31) / 32;             // 3125 for N=100k
  const int gblocks = tiles32 < 16384 ? tiles32 : 16384;
  const int nchunk = (n_edges + BCHUNK - 1) / BCHUNK;
  const int pblocks = nchunk < 1024 ? nchunk : 1024;
  dim3 blk(256);

  // gtail zero-init (binpack adds the t*CAP_PACK base itself)
  hipMemsetAsync(gtail, 0, NBMAX * sizeof(int), stream);
  // K12: fused layer-1 dual GEMM + edge binpack (independent block halves)
  prep_kernel<<<pblocks + 1024, blk, 0, stream>>>(
      feats, W1, Wr1, br1, xw1, res1, n_nodes, src, dst, gtail, packed,
      n_edges, pblocks);
  // K3: per-bucket counting sort -> csr_off, csr_src (+ csr_off tail)
  bucket_csr_kernel<<<nbuckets, blk, 0, stream>>>(packed, gtail, csr_off,
                                                  csr_src, n_nodes, nbuckets,
                                                  n_edges);
  // K4: gather1 + combine + layer-2 dual GEMM (h1 stays in LDS)
  gather_gemm_kernel<<<gblocks, blk, 0, stream>>>(
      xw1, res1, b1, csr_off, csr_src, W2, Wr2, br2, xw2, res2, n_nodes);
  // K5: final gather + combine -> out
  gather_combine_kernel<<<gblocks, blk, 0, stream>>>(
      xw2, res2, b2, csr_off, csr_src, out, n_nodes);
}

// Round 6
// 227.377 us; speedup vs baseline: 1.2958x; 1.0033x over previous
//
#include <hip/hip_runtime.h>

#define D 64
#define NBMAX 256       // bucket count padded to 256 (real NB = ceil(N/512) = 196)
#define BCHUNK 4096     // edges per binpack block-iteration
#define CAP 8192        // LDS staging cap in bucket_csr (mean 6122, +26 sigma)
#define CAP_PACK 12288  // fixed per-bucket region in packed[] (self-allocating)

typedef unsigned short ushort_t;
typedef __attribute__((ext_vector_type(8))) short bf16x8;
typedef __attribute__((ext_vector_type(4))) float floatx4;

static __device__ __forceinline__ ushort_t f2bf(float x) {
  unsigned u = __float_as_uint(x);
  unsigned r = (u + 0x7FFF + ((u >> 16) & 1)) >> 16;  // RNE
  return (ushort_t)r;
}
static __device__ __forceinline__ float bf2f(ushort_t u) {
  return __uint_as_float(((unsigned)u) << 16);
}

// Accumulate one 16B (8 x bf16) row slice into 4 float2 accumulators.
static __device__ __forceinline__ void addrow(const uint4 v, float2& a0,
                                              float2& a1, float2& a2,
                                              float2& a3) {
  a0.x += __uint_as_float(v.x << 16);
  a0.y += __uint_as_float(v.x & 0xffff0000u);
  a1.x += __uint_as_float(v.y << 16);
  a1.y += __uint_as_float(v.y & 0xffff0000u);
  a2.x += __uint_as_float(v.z << 16);
  a2.y += __uint_as_float(v.z & 0xffff0000u);
  a3.x += __uint_as_float(v.w << 16);
  a3.y += __uint_as_float(v.w & 0xffff0000u);
}

// Load 4 row-slices (chunk CB..CB+3 of this group's edge list). Masked slots
// return zeros so accumulation is unconditional.
#define GLOAD4(T0, T1, T2, T3, IR, OFF, CB)                                    \
  do {                                                                         \
    const int s0_ = __shfl((IR), gbase + (OFF) + 0, 64);                       \
    const int s1_ = __shfl((IR), gbase + (OFF) + 1, 64);                       \
    const int s2_ = __shfl((IR), gbase + (OFF) + 2, 64);                       \
    const int s3_ = __shfl((IR), gbase + (OFF) + 3, 64);                       \
    T0 = ((CB) + 0 < m) ? *(const uint4*)(tab + ((size_t)s0_ << 6) + off16)    \
                        : z4;                                                  \
    T1 = ((CB) + 1 < m) ? *(const uint4*)(tab + ((size_t)s1_ << 6) + off16)    \
                        : z4;                                                  \
    T2 = ((CB) + 2 < m) ? *(const uint4*)(tab + ((size_t)s2_ << 6) + off16)    \
                        : z4;                                                  \
    T3 = ((CB) + 3 < m) ? *(const uint4*)(tab + ((size_t)s3_ << 6) + off16)    \
                        : z4;                                                  \
  } while (0)

#define ACC4(T0, T1, T2, T3)    \
  do {                          \
    addrow(T0, c0, c1, c2, c3); \
    addrow(T1, c0, c1, c2, c3); \
    addrow(T2, c0, c1, c2, c3); \
    addrow(T3, c0, c1, c2, c3); \
  } while (0)

// Group-per-node gather: 8-lane group owns node (e0..e1), each lane owns a
// fixed 16B column slice. Up to 32 edges via prefetched indices + 2-deep
// pipelined chunks of 4 row loads; deg>32 tail is a rare serial loop.
// Must be called by all 64 lanes of the wave (shfl participation).
static __device__ __forceinline__ void gather_node8(
    const ushort_t* __restrict__ tab, const int* __restrict__ csr_src, int e0,
    int e1, int sub8, int gbase, float2& c0, float2& c1, float2& c2,
    float2& c3) {
  const int off16 = sub8 << 3;  // ushort units: 16B per lane
  const int m = e1 - e0;
  // prefetch up to 32 indices (4 independent loads per lane)
  const int ir0 = (e0 + 0 + sub8 < e1) ? csr_src[e0 + 0 + sub8] : 0;
  const int ir1 = (e0 + 8 + sub8 < e1) ? csr_src[e0 + 8 + sub8] : 0;
  const int ir2 = (e0 + 16 + sub8 < e1) ? csr_src[e0 + 16 + sub8] : 0;
  const int ir3 = (e0 + 24 + sub8 < e1) ? csr_src[e0 + 24 + sub8] : 0;
  // wave-uniform chunk count from max degree (m uniform within group)
  int mm = m;
  mm = max(mm, __shfl_xor(mm, 8, 64));
  mm = max(mm, __shfl_xor(mm, 16, 64));
  mm = max(mm, __shfl_xor(mm, 32, 64));
  const int nch = __builtin_amdgcn_readfirstlane(min((mm + 3) >> 2, 8));
  const uint4 z4 = make_uint4(0, 0, 0, 0);
  uint4 A0, A1, A2, A3, B0, B1, B2, B3;
  if (nch > 0) {
    GLOAD4(A0, A1, A2, A3, ir0, 0, 0);
    if (nch > 1) GLOAD4(B0, B1, B2, B3, ir0, 4, 4);
    ACC4(A0, A1, A2, A3);
    if (nch > 1) {
      if (nch > 2) GLOAD4(A0, A1, A2, A3, ir1, 0, 8);
      ACC4(B0, B1, B2, B3);
      if (nch > 2) {
        if (nch > 3) GLOAD4(B0, B1, B2, B3, ir1, 4, 12);
        ACC4(A0, A1, A2, A3);
        if (nch > 3) {
          if (nch > 4) GLOAD4(A0, A1, A2, A3, ir2, 0, 16);
          ACC4(B0, B1, B2, B3);
          if (nch > 4) {
            if (nch > 5) GLOAD4(B0, B1, B2, B3, ir2, 4, 20);
            ACC4(A0, A1, A2, A3);
            if (nch > 5) {
              if (nch > 6) GLOAD4(A0, A1, A2, A3, ir3, 0, 24);
              ACC4(B0, B1, B2, B3);
              if (nch > 6) {
                if (nch > 7) GLOAD4(B0, B1, B2, B3, ir3, 4, 28);
                ACC4(A0, A1, A2, A3);
                if (nch > 7) ACC4(B0, B1, B2, B3);
              }
            }
          }
        }
      }
    }
  }
  // rare deg>32 tail (group-uniform loop, exec-masked per group)
  for (int eb = e0 + 32; eb < e1; ++eb) {
    const int ii = csr_src[eb];
    const uint4 tv = *(const uint4*)(tab + ((size_t)ii << 6) + off16);
    addrow(tv, c0, c1, c2, c3);
  }
}

// ---- K12: FUSED layer-1 dual GEMM + edge binpack ----
// Blocks [0,pblocks): binpack (chunk-local LDS sort -> per-bucket fixed
// regions; gtail is pre-zeroed by hipMemsetAsync, base t*CAP_PACK added here).
// Blocks [pblocks, pblocks+1024): layer-1 MFMA GEMM + residual.
__global__ __launch_bounds__(256) void prep_kernel(
    const float* __restrict__ x, const float* __restrict__ W,
    const float* __restrict__ Wr, const float* __restrict__ br,
    ushort_t* __restrict__ xw, ushort_t* __restrict__ res, int n_nodes,
    const int* __restrict__ src, const int* __restrict__ dst,
    int* __restrict__ gtail, unsigned* __restrict__ packed, int n_edges,
    int pblocks) {
  __shared__ int start[NBMAX], cur[NBMAX], gpos[NBMAX];
  __shared__ unsigned sorted[BCHUNK];
  __shared__ unsigned char bktid[BCHUNK];
  if ((int)blockIdx.x < pblocks) {
    // ================= binpack half =================
    const int t = threadIdx.x;
    const int nchunk = (n_edges + BCHUNK - 1) / BCHUNK;
    for (int c = blockIdx.x; c < nchunk; c += pblocks) {
      cur[t] = 0;
      __syncthreads();
      const int e0 = c * BCHUNK;
      const int m = min(BCHUNK, n_edges - e0);
      int bk[16];
      unsigned pk[16];
#pragma unroll
      for (int k = 0; k < 16; ++k) {
        const int e = e0 + k * 256 + t;
        if (e < n_edges) {
          const int d = dst[e];
          const int s = src[e];
          bk[k] = d >> 9;
          pk[k] = ((unsigned)(d & 511) << 23) | (unsigned)s;
          atomicAdd(&cur[bk[k]], 1);
        } else {
          bk[k] = -1;
        }
      }
      __syncthreads();
      const int h = cur[t];
      start[t] = h;
      __syncthreads();
      for (int off = 1; off < NBMAX; off <<= 1) {
        const int v = (t >= off) ? start[t - off] : 0;
        __syncthreads();
        start[t] += v;
        __syncthreads();
      }
      const int excl = start[t] - h;
      __syncthreads();
      start[t] = excl;
      cur[t] = excl;
      __syncthreads();
#pragma unroll
      for (int k = 0; k < 16; ++k) {
        if (bk[k] >= 0) {
          const int pos = atomicAdd(&cur[bk[k]], 1);
          sorted[pos] = pk[k];
          bktid[pos] = (unsigned char)bk[k];
        }
      }
      __syncthreads();
      if (h > 0) gpos[t] = t * CAP_PACK + atomicAdd(&gtail[t], h);
      __syncthreads();
      for (int j = t; j < m; j += 256) {
        const int b = bktid[j];
        packed[gpos[b] + j - start[b]] = sorted[j];
      }
      __syncthreads();
    }
    return;
  }
  // ================= layer-1 GEMM half =================
  const int lane = threadIdx.x & 63;
  const int wid = threadIdx.x >> 6;
  const int sub = lane & 15;
  const int q = lane >> 4;

  bf16x8 bW[4][2], bR[4][2];
#pragma unroll
  for (int t = 0; t < 4; ++t) {
#pragma unroll
    for (int s = 0; s < 2; ++s) {
      bf16x8 fw, fr;
#pragma unroll
      for (int j = 0; j < 8; ++j) {
        const int k = s * 32 + q * 8 + j;
        const int c = t * 16 + sub;
        fw[j] = (short)f2bf(W[k * D + c]);
        fr[j] = (short)f2bf(Wr[k * D + c]);
      }
      bW[t][s] = fw;
      bR[t][s] = fr;
    }
  }
  float brv[4];
#pragma unroll
  for (int t = 0; t < 4; ++t) brv[t] = br[t * 16 + sub];

  const int gb = (int)gridDim.x - pblocks;
  const int n_tiles = (n_nodes + 15) >> 4;
  const int wave_id = ((int)blockIdx.x - pblocks) * 4 + wid;
  const int n_waves = gb * 4;
  for (int tile = wave_id; tile < n_tiles; tile += n_waves) {
    const int n0 = tile << 4;
    const bool full = (n0 + 16 <= n_nodes);
    bf16x8 a0h, a0l, a1h, a1l;
    float v[16];
    if (full) {
      const float* xp = x + (size_t)(n0 + sub) * D + q * 8;
      *(float4*)(v + 0)  = *(const float4*)(xp);
      *(float4*)(v + 4)  = *(const float4*)(xp + 4);
      *(float4*)(v + 8)  = *(const float4*)(xp + 32);
      *(float4*)(v + 12) = *(const float4*)(xp + 36);
    } else {
      const bool ok = (n0 + sub) < n_nodes;
      const float* xp = x + (size_t)(n0 + sub) * D + q * 8;
#pragma unroll
      for (int j = 0; j < 8; ++j) {
        v[j] = ok ? xp[j] : 0.f;
        v[8 + j] = ok ? xp[32 + j] : 0.f;
      }
    }
#pragma unroll
    for (int j = 0; j < 8; ++j) {
      const ushort_t h0 = f2bf(v[j]);
      a0h[j] = (short)h0;
      a0l[j] = (short)f2bf(v[j] - bf2f(h0));
      const ushort_t h1 = f2bf(v[8 + j]);
      a1h[j] = (short)h1;
      a1l[j] = (short)f2bf(v[8 + j] - bf2f(h1));
    }
    floatx4 accW[4], accR[4];
#pragma unroll
    for (int t = 0; t < 4; ++t) {
      accW[t] = (floatx4){0.f, 0.f, 0.f, 0.f};
      accR[t] = (floatx4){0.f, 0.f, 0.f, 0.f};
    }
#pragma unroll
    for (int t = 0; t < 4; ++t) {
      accW[t] = __builtin_amdgcn_mfma_f32_16x16x32_bf16(a0h, bW[t][0], accW[t], 0, 0, 0);
      accW[t] = __builtin_amdgcn_mfma_f32_16x16x32_bf16(a0l, bW[t][0], accW[t], 0, 0, 0);
      accW[t] = __builtin_amdgcn_mfma_f32_16x16x32_bf16(a1h, bW[t][1], accW[t], 0, 0, 0);
      accW[t] = __builtin_amdgcn_mfma_f32_16x16x32_bf16(a1l, bW[t][1], accW[t], 0, 0, 0);
      accR[t] = __builtin_amdgcn_mfma_f32_16x16x32_bf16(a0h, bR[t][0], accR[t], 0, 0, 0);
      accR[t] = __builtin_amdgcn_mfma_f32_16x16x32_bf16(a0l, bR[t][0], accR[t], 0, 0, 0);
      accR[t] = __builtin_amdgcn_mfma_f32_16x16x32_bf16(a1h, bR[t][1], accR[t], 0, 0, 0);
      accR[t] = __builtin_amdgcn_mfma_f32_16x16x32_bf16(a1l, bR[t][1], accR[t], 0, 0, 0);
    }
    if (full) {
#pragma unroll
      for (int t = 0; t < 4; ++t) {
#pragma unroll
        for (int i = 0; i < 4; ++i) {
          const size_t r = (size_t)(n0 + q * 4 + i) * D + t * 16 + sub;
          xw[r] = f2bf(accW[t][i]);
          res[r] = f2bf(fmaxf(accR[t][i] + brv[t], 0.f));
        }
      }
    } else {
#pragma unroll
      for (int t = 0; t < 4; ++t) {
#pragma unroll
        for (int i = 0; i < 4; ++i) {
          const int rr = n0 + q * 4 + i;
          if (rr < n_nodes) {
            const size_t r = (size_t)rr * D + t * 16 + sub;
            xw[r] = f2bf(accW[t][i]);
            res[r] = f2bf(fmaxf(accR[t][i] + brv[t], 0.f));
          }
        }
      }
    }
  }
}

// ---- K3: one block per bucket. LDS scan of gtail counts -> exact bases;
// LDS counting sort; coalesced csr_off/csr_src out; writes csr_off tail.
__global__ __launch_bounds__(256) void bucket_csr_kernel(
    const unsigned* __restrict__ packed, const int* __restrict__ gtail,
    int* __restrict__ csr_off, int* __restrict__ csr_src, int n_nodes,
    int nbuckets, int n_edges) {
  __shared__ int scnt[NBMAX], sexc[NBMAX];
  __shared__ int sc[2][512];
  __shared__ int cur[512];
  __shared__ unsigned outbuf[CAP];
  const int b = blockIdx.x;
  const int t = threadIdx.x;
  if (b == 0 && t == 0) csr_off[n_nodes] = n_edges;
  const int cb = (t < nbuckets) ? gtail[t] : 0;
  scnt[t] = cb;
  sexc[t] = cb;
  __syncthreads();
  for (int off = 1; off < NBMAX; off <<= 1) {
    const int v = (t >= off) ? sexc[t - off] : 0;
    __syncthreads();
    sexc[t] += v;
    __syncthreads();
  }
  sexc[t] -= scnt[t];  // exclusive
  __syncthreads();
  const int base = sexc[b];
  const int cntE = scnt[b];
  const unsigned* pk = packed + (size_t)b * CAP_PACK;

  const int n0 = b << 9;
  const int nn = min(512, n_nodes - n0);
  cur[t] = 0;
  cur[t + 256] = 0;
  __syncthreads();
  for (int i = t; i < cntE; i += 256) atomicAdd(&cur[pk[i] >> 23], 1);
  __syncthreads();
  const int h0 = cur[t];
  const int h1 = cur[t + 256];
  sc[0][t] = h0;
  sc[0][t + 256] = h1;
  __syncthreads();
  int pin = 0;
  for (int off = 1; off < 512; off <<= 1) {
    sc[1 - pin][t] = sc[pin][t] + ((t >= off) ? sc[pin][t - off] : 0);
    sc[1 - pin][t + 256] =
        sc[pin][t + 256] + ((t + 256 >= off) ? sc[pin][t + 256 - off] : 0);
    __syncthreads();
    pin ^= 1;
  }
  const int excl0 = sc[pin][t] - h0;
  const int excl1 = sc[pin][t + 256] - h1;
  if (t < nn) csr_off[n0 + t] = base + excl0;
  if (t + 256 < nn) csr_off[n0 + t + 256] = base + excl1;
  cur[t] = excl0;
  cur[t + 256] = excl1;
  __syncthreads();
  if (cntE <= CAP) {
    for (int i = t; i < cntE; i += 256) {
      const unsigned u = pk[i];
      const int pos = atomicAdd(&cur[u >> 23], 1);
      outbuf[pos] = u & 0x7FFFFFu;
    }
    __syncthreads();
    for (int j = t; j < cntE; j += 256) csr_src[base + j] = (int)outbuf[j];
  } else {  // overflow fallback
    for (int i = t; i < cntE; i += 256) {
      const unsigned u = pk[i];
      const int pos = atomicAdd(&cur[u >> 23], 1);
      csr_src[base + pos] = (int)(u & 0x7FFFFFu);
    }
  }
}

// ---- K4: fused gather1 + combine + gemm2, 32-row tiles ----
// LDS = h_tile only (8.7KB). Weight fragments loaded from global INSIDE the
// gemm phase (live range does not span the gather -> low gather-phase VGPR
// pressure, no LDS round-trip, no startup barrier). b1 read directly at
// combine. res1 row prefetched before the gather (independent load).
// PLAIN launch bounds (rounds 3/4 lesson: forced caps => scratch spill).
__global__ __launch_bounds__(256) void gather_gemm_kernel(
    const ushort_t* __restrict__ xw1, const ushort_t* __restrict__ res1,
    const float* __restrict__ b1v, const int* __restrict__ csr_off,
    const int* __restrict__ csr_src, const float* __restrict__ W2,
    const float* __restrict__ Wr2, const float* __restrict__ br2,
    ushort_t* __restrict__ xw2, ushort_t* __restrict__ res2, int n_nodes) {
  const int lane = threadIdx.x & 63;
  const int w = threadIdx.x >> 6;
  const int sub = lane & 15;  // gemm phase
  const int q = lane >> 4;    // gemm phase
  const int sub8 = lane & 7;  // gather phase
  const int g = lane >> 3;
  const int gbase = lane & 56;
  __shared__ float h_tile[32][68];

  const float brl2 = br2[w * 16 + sub];

  const int n_tiles = (n_nodes + 31) >> 5;
  for (int tile = blockIdx.x; tile < n_tiles; tile += gridDim.x) {
    const int n0 = tile << 5;
    const int nb = n0 + w * 8;
    // 9 consecutive csr_off entries via lanes 0..8 (clamped; csr_off[n_nodes]
    // valid == n_edges, set by K3). Clamped nodes get m=0.
    const int offv = csr_off[min(nb + (lane < 9 ? lane : 8), n_nodes)];
    const int e0 = __shfl(offv, g, 64);
    const int e1 = __shfl(offv, g + 1, 64);
    const int n = nb + g;
    // prefetch res1 row + bias (independent of gather result)
    uint4 rv = make_uint4(0, 0, 0, 0);
    if (n < n_nodes)
      rv = *(const uint4*)(res1 + ((size_t)n << 6) + (sub8 << 3));
    const float4 blo = *(const float4*)(b1v + sub8 * 8);
    const float4 bhi = *(const float4*)(b1v + sub8 * 8 + 4);
    float2 c0 = {0.f, 0.f}, c1 = {0.f, 0.f}, c2 = {0.f, 0.f}, c3 = {0.f, 0.f};
    gather_node8(xw1, csr_src, e0, e1, sub8, gbase, c0, c1, c2, c3);
    const int row = (w << 3) + g;
    if (n < n_nodes) {
      float4 lo, hi;
      lo.x = fmaxf(c0.x + blo.x, 0.f) + __uint_as_float(rv.x << 16);
      lo.y = fmaxf(c0.y + blo.y, 0.f) + __uint_as_float(rv.x & 0xffff0000u);
      lo.z = fmaxf(c1.x + blo.z, 0.f) + __uint_as_float(rv.y << 16);
      lo.w = fmaxf(c1.y + blo.w, 0.f) + __uint_as_float(rv.y & 0xffff0000u);
      hi.x = fmaxf(c2.x + bhi.x, 0.f) + __uint_as_float(rv.z << 16);
      hi.y = fmaxf(c2.y + bhi.y, 0.f) + __uint_as_float(rv.z & 0xffff0000u);
      hi.z = fmaxf(c3.x + bhi.z, 0.f) + __uint_as_float(rv.w << 16);
      hi.w = fmaxf(c3.y + bhi.w, 0.f) + __uint_as_float(rv.w & 0xffff0000u);
      *(float4*)(&h_tile[row][sub8 * 8]) = lo;
      *(float4*)(&h_tile[row][sub8 * 8 + 4]) = hi;
    } else {
      *(float4*)(&h_tile[row][sub8 * 8]) = make_float4(0.f, 0.f, 0.f, 0.f);
      *(float4*)(&h_tile[row][sub8 * 8 + 4]) = make_float4(0.f, 0.f, 0.f, 0.f);
    }
    __syncthreads();
    // ---- gemm2: wave w computes cols w*16..+15 for both 16-row sub-tiles ----
    // weight fragments loaded here (global, L2-hot); not live during gather
    bf16x8 w0f, w1f, r0f, r1f;
    {
#pragma unroll
      for (int s = 0; s < 2; ++s) {
        bf16x8 fw, fr;
#pragma unroll
        for (int j = 0; j < 8; ++j) {
          const int k = s * 32 + q * 8 + j;
          const int c = w * 16 + sub;
          fw[j] = (short)f2bf(W2[k * D + c]);
          fr[j] = (short)f2bf(Wr2[k * D + c]);
        }
        if (s == 0) { w0f = fw; r0f = fr; } else { w1f = fw; r1f = fr; }
      }
    }
#pragma unroll
    for (int st = 0; st < 2; ++st) {
      const float* hrow = &h_tile[st * 16 + sub][0];
      bf16x8 a0h, a0l, a1h, a1l;
      {
        const float4 p0 = *(const float4*)(hrow + q * 8);
        const float4 p1 = *(const float4*)(hrow + q * 8 + 4);
        const float vv[8] = {p0.x, p0.y, p0.z, p0.w, p1.x, p1.y, p1.z, p1.w};
#pragma unroll
        for (int j = 0; j < 8; ++j) {
          const ushort_t h0 = f2bf(vv[j]);
          a0h[j] = (short)h0;
          a0l[j] = (short)f2bf(vv[j] - bf2f(h0));
        }
      }
      {
        const float4 p2 = *(const float4*)(hrow + 32 + q * 8);
        const float4 p3 = *(const float4*)(hrow + 32 + q * 8 + 4);
        const float vv[8] = {p2.x, p2.y, p2.z, p2.w, p3.x, p3.y, p3.z, p3.w};
#pragma unroll
        for (int j = 0; j < 8; ++j) {
          const ushort_t h1 = f2bf(vv[j]);
          a1h[j] = (short)h1;
          a1l[j] = (short)f2bf(vv[j] - bf2f(h1));
        }
      }
      floatx4 accW = (floatx4){0.f, 0.f, 0.f, 0.f};
      floatx4 accR = (floatx4){0.f, 0.f, 0.f, 0.f};
      accW = __builtin_amdgcn_mfma_f32_16x16x32_bf16(a0h, w0f, accW, 0, 0, 0);
      accW = __builtin_amdgcn_mfma_f32_16x16x32_bf16(a0l, w0f, accW, 0, 0, 0);
      accW = __builtin_amdgcn_mfma_f32_16x16x32_bf16(a1h, w1f, accW, 0, 0, 0);
      accW = __builtin_amdgcn_mfma_f32_16x16x32_bf16(a1l, w1f, accW, 0, 0, 0);
      accR = __builtin_amdgcn_mfma_f32_16x16x32_bf16(a0h, r0f, accR, 0, 0, 0);
      accR = __builtin_amdgcn_mfma_f32_16x16x32_bf16(a0l, r0f, accR, 0, 0, 0);
      accR = __builtin_amdgcn_mfma_f32_16x16x32_bf16(a1h, r1f, accR, 0, 0, 0);
      accR = __builtin_amdgcn_mfma_f32_16x16x32_bf16(a1l, r1f, accR, 0, 0, 0);
#pragma unroll
      for (int i = 0; i < 4; ++i) {
        const int rr = n0 + st * 16 + q * 4 + i;
        if (rr < n_nodes) {
          const size_t r = (size_t)rr * D + w * 16 + sub;
          xw2[r] = f2bf(accW[i]);
          res2[r] = f2bf(fmaxf(accR[i] + brl2, 0.f));
        }
      }
    }
    __syncthreads();  // h_tile reused next tile
  }
}

// ---- K5: final gather + combine -> out (group-per-node gather) ----
// Plain launch_bounds; res row prefetched before the gather.
__global__ __launch_bounds__(256) void gather_combine_kernel(
    const ushort_t* __restrict__ xw, const ushort_t* __restrict__ res,
    const float* __restrict__ b, const int* __restrict__ csr_off,
    const int* __restrict__ csr_src, float* __restrict__ out, int n_nodes) {
  const int lane = threadIdx.x & 63;
  const int w = threadIdx.x >> 6;
  const int sub8 = lane & 7;
  const int g = lane >> 3;
  const int gbase = lane & 56;
  const int n_tiles = (n_nodes + 31) >> 5;
  for (int tile = blockIdx.x; tile < n_tiles; tile += gridDim.x) {
    const int nb = (tile << 5) + w * 8;
    const int offv = csr_off[min(nb + (lane < 9 ? lane : 8), n_nodes)];
    const int e0 = __shfl(offv, g, 64);
    const int e1 = __shfl(offv, g + 1, 64);
    const int n = nb + g;
    uint4 rv = make_uint4(0, 0, 0, 0);
    if (n < n_nodes)
      rv = *(const uint4*)(res + ((size_t)n << 6) + (sub8 << 3));
    const float4 blo = *(const float4*)(b + sub8 * 8);
    const float4 bhi = *(const float4*)(b + sub8 * 8 + 4);
    float2 c0 = {0.f, 0.f}, c1 = {0.f, 0.f}, c2 = {0.f, 0.f}, c3 = {0.f, 0.f};
    gather_node8(xw, csr_src, e0, e1, sub8, gbase, c0, c1, c2, c3);
    if (n < n_nodes) {
      float4 lo, hi;
      lo.x = fmaxf(c0.x + blo.x, 0.f) + __uint_as_float(rv.x << 16);
      lo.y = fmaxf(c0.y + blo.y, 0.f) + __uint_as_float(rv.x & 0xffff0000u);
      lo.z = fmaxf(c1.x + blo.z, 0.f) + __uint_as_float(rv.y << 16);
      lo.w = fmaxf(c1.y + blo.w, 0.f) + __uint_as_float(rv.y & 0xffff0000u);
      hi.x = fmaxf(c2.x + bhi.x, 0.f) + __uint_as_float(rv.z << 16);
      hi.y = fmaxf(c2.y + bhi.y, 0.f) + __uint_as_float(rv.z & 0xffff0000u);
      hi.z = fmaxf(c3.x + bhi.z, 0.f) + __uint_as_float(rv.w << 16);
      hi.w = fmaxf(c3.y + bhi.w, 0.f) + __uint_as_float(rv.w & 0xffff0000u);
      *(float4*)(out + ((size_t)n << 6) + sub8 * 8) = lo;
      *(float4*)(out + ((size_t)n << 6) + sub8 * 8 + 4) = hi;
    }
  }
}

extern "C" void kernel_launch(void* const* d_in, const int* in_sizes, int n_in,
                              void* d_out, int out_size, void* d_ws, size_t ws_size,
                              hipStream_t stream) {
  const float* feats = (const float*)d_in[0];
  const float* W1  = (const float*)d_in[1];
  const float* b1  = (const float*)d_in[2];
  const float* Wr1 = (const float*)d_in[3];
  const float* br1 = (const float*)d_in[4];
  const float* W2  = (const float*)d_in[5];
  const float* b2  = (const float*)d_in[6];
  const float* Wr2 = (const float*)d_in[7];
  const float* br2 = (const float*)d_in[8];
  const int* src = (const int*)d_in[9];
  const int* dst = (const int*)d_in[10];
  const int n_nodes = in_sizes[0] / D;
  const int n_edges = in_sizes[9];
  float* out = (float*)d_out;

  const int nbuckets = (n_nodes + 511) >> 9;  // 196 for N=100k

  // workspace layout (~70 MB)
  ushort_t* xw1 = (ushort_t*)d_ws;                     // n_nodes*D bf16
  ushort_t* res1 = xw1 + (size_t)n_nodes * D;
  ushort_t* xw2 = res1 + (size_t)n_nodes * D;
  ushort_t* res2 = xw2 + (size_t)n_nodes * D;
  int* csr_off = (int*)(res2 + (size_t)n_nodes * D);   // n_nodes+1
  int* csr_src = csr_off + (n_nodes + 1);              // n_edges
  int* gtail = csr_src + n_edges;                      // NBMAX
  unsigned* packed = (unsigned*)(gtail + NBMAX);       // NBMAX*CAP_PACK

  const int tiles32 = (n_nodes + 31) / 32;             // 3125 for N=100k
  const int gblocks = tiles32 < 16384 ? tiles32 : 16384;
  const int nchunk = (n_edges + BCHUNK - 1) / BCHUNK;
  const int pblocks = nchunk < 1024 ? nchunk : 1024;
  dim3 blk(256);

  // gtail zero-init (binpack adds the t*CAP_PACK base itself)
  hipMemsetAsync(gtail, 0, NBMAX * sizeof(int), stream);
  // K12: fused layer-1 dual GEMM + edge binpack (independent block halves)
  prep_kernel<<<pblocks + 1024, blk, 0, stream>>>(
      feats, W1, Wr1, br1, xw1, res1, n_nodes, src, dst, gtail, packed,
      n_edges, pblocks);
  // K3: per-bucket counting sort -> csr_off, csr_src (+ csr_off tail)
  bucket_csr_kernel<<<nbuckets, blk, 0, stream>>>(packed, gtail, csr_off,
                                                  csr_src, n_nodes, nbuckets,
                                                  n_edges);
  // K4: gather1 + combine + layer-2 dual GEMM (h1 stays in LDS)
  gather_gemm_kernel<<<gblocks, blk, 0, stream>>>(
      xw1, res1, b1, csr_off, csr_src, W2, Wr2, br2, xw2, res2, n_nodes);
  // K5: final gather + combine -> out
  gather_combine_kernel<<<gblocks, blk, 0, stream>>>(
      xw2, res2, b2, csr_off, csr_src, out, n_nodes);
}